// Round 11
// baseline (260.403 us; speedup 1.0000x reference)
//
#include <hip/hip_runtime.h>
#include <math.h>

#define B_ 4
#define S_ 2048
#define E_ 1024
#define H_ 16
#define D_ 64
#define MTOT (B_*S_)

typedef _Float16 half8v __attribute__((ext_vector_type(8)));
typedef _Float16 half4v __attribute__((ext_vector_type(4)));
typedef float f32x4 __attribute__((ext_vector_type(4)));
typedef float f32x16 __attribute__((ext_vector_type(16)));
typedef unsigned uint4v __attribute__((ext_vector_type(4)));

typedef __attribute__((address_space(1))) const void gconst_void;
typedef __attribute__((address_space(3))) void lds_void;

#define MFMA16(a,b,c) __builtin_amdgcn_mfma_f32_16x16x32_f16((a),(b),(c),0,0,0)
#define MFMA32(a,b,c) __builtin_amdgcn_mfma_f32_32x32x16_f16((a),(b),(c),0,0,0)

#define QSCALE 0.18033688011112042f  /* 0.125 * log2(e): folded into Q at projection */

// pack two f32 -> u32 of 2 f16 (RTZ)
static __device__ __forceinline__ unsigned cvt_pk_u32(float a, float b) {
  return __builtin_bit_cast(unsigned, __builtin_amdgcn_cvt_pkrtz(a, b));
}

// {lo', hi'} = cross-half swap: lo' = {A.lo, B.lo}, hi' = {A.hi, B.hi}
#if __has_builtin(__builtin_amdgcn_permlane32_swap)
static __device__ __forceinline__ void pl32_swap(unsigned a, unsigned b,
                                                 unsigned& rlo, unsigned& rhi) {
  auto r = __builtin_amdgcn_permlane32_swap(a, b, false, false);
  rlo = r[0]; rhi = r[1];
}
#else
static __device__ __forceinline__ void pl32_swap(unsigned a, unsigned b,
                                                 unsigned& rlo, unsigned& rhi) {
  const int hi = (threadIdx.x & 63) >> 5;
  unsigned t = __shfl_xor(hi ? a : b, 32);
  rlo = hi ? t : a;
  rhi = hi ? b : t;
}
#endif

// partner-lane (lane^32) value of v
static __device__ __forceinline__ float partner32(float v, int hi) {
  unsigned u = __builtin_bit_cast(unsigned, v);
  unsigned lo_, hi_;
  pl32_swap(u, u, lo_, hi_);
  return __builtin_bit_cast(float, hi ? lo_ : hi_);
}

// ---------------- fp32 -> fp16 convert ----------------
__global__ __launch_bounds__(256) void cvt_f32_f16(const float* __restrict__ in,
                                                   _Float16* __restrict__ out, int n) {
  int i = (blockIdx.x * 256 + threadIdx.x) * 4;
  if (i >= n) return;
  float4 v = *(const float4*)(in + i);
  half4v o;
  o[0] = (_Float16)v.x; o[1] = (_Float16)v.y; o[2] = (_Float16)v.z; o[3] = (_Float16)v.w;
  *(half4v*)(out + i) = o;
}

// ---------------- mask prep (format auto-detect) ----------------
__global__ __launch_bounds__(1024) void mask_prep(const unsigned char* __restrict__ mraw,
                                                  _Float16* __restrict__ maskH,
                                                  float* __restrict__ qmask) {
  __shared__ int flags[2];
  const int tid = threadIdx.x;
  if (tid < 2) flags[tid] = 1;
  __syncthreads();
  const unsigned int* w = (const unsigned int*)mraw;
  for (int i = tid; i < 2048; i += 1024) {
    unsigned int v = w[i];
    if (!(v == 0u || v == 1u)) flags[0] = 0;
    if (!(v == 0u || v == 0x3f800000u)) flags[1] = 0;
  }
  __syncthreads();
  const int is_i32 = flags[0], is_f32 = flags[1];
  for (int i = tid; i < B_ * S_; i += 1024) {
    int mv;
    if (is_i32)      mv = ((const int*)mraw)[i];
    else if (is_f32) mv = (((const unsigned int*)mraw)[i] != 0u);
    else             mv = (mraw[i] != 0);
    maskH[i]  = mv ? (_Float16)0.0f : (_Float16)(-60000.0f);
    qmask[i]  = mv ? 1.0f : 0.0f;
  }
}

// ---------------- GEMM staging: 128 rows x 32 f16 cols -> LDS (linear) ----------------
__device__ __forceinline__ void stage128x32(const _Float16* __restrict__ g, int ld,
                                            _Float16* lds, int wid, int lane) {
#pragma unroll
  for (int j = 0; j < 2; ++j) {
    const int c = j * 256 + wid * 64 + lane;
    const _Float16* src = g + (size_t)(c >> 2) * ld + (c & 3) * 8;
    _Float16* dst = lds + (size_t)(j * 256 + wid * 64) * 8;
    __builtin_amdgcn_global_load_lds((gconst_void*)src, (lds_void*)dst, 16, 0, 0);
  }
}

// ---------------- QKV projection GEMM ----------------
// Q stored row-major (B,H,S,D), PRE-SCALED by QSCALE (softmax in log2 domain).
// K stored FRAGMENT-LINEAR: Kf[bh][s>>5][d>>4][s&31][d&15]
// V stored FRAGMENT-LINEAR: Vf[bh][s>>4][d][s&15]
__global__ __launch_bounds__(256) void qkv_gemm(
    const _Float16* __restrict__ xh,
    const _Float16* __restrict__ wq, const _Float16* __restrict__ wk, const _Float16* __restrict__ wv,
    const float* __restrict__ bq, const float* __restrict__ bkp, const float* __restrict__ bvp,
    _Float16* __restrict__ Qh, _Float16* __restrict__ Kh, _Float16* __restrict__ Vth) {
  __shared__ _Float16 As[128 * 32];
  __shared__ _Float16 Bs[128 * 32];
  const int tid = threadIdx.x, lane = tid & 63, wid = tid >> 6;
  const int g = lane >> 4, r16 = lane & 15;
  const int bm = blockIdx.x * 128, bn = blockIdx.y * 128;
  const int z = blockIdx.z;
  const _Float16* w = (z == 0) ? wq : (z == 1) ? wk : wv;
  const float* bias = (z == 0) ? bq : (z == 1) ? bkp : bvp;
  const int wr = wid >> 1, wc = wid & 1;
  f32x4 acc[4][4] = {};
  for (int k0 = 0; k0 < E_; k0 += 32) {
    stage128x32(xh + (size_t)bm * E_ + k0, E_, As, wid, lane);
    stage128x32(w + (size_t)bn * E_ + k0, E_, Bs, wid, lane);
    __syncthreads();
    half8v a[4], bf[4];
#pragma unroll
    for (int i = 0; i < 4; ++i) a[i] = *(const half8v*)&As[(wr * 64 + i * 16 + r16) * 32 + g * 8];
#pragma unroll
    for (int i = 0; i < 4; ++i) bf[i] = *(const half8v*)&Bs[(wc * 64 + i * 16 + r16) * 32 + g * 8];
#pragma unroll
    for (int i = 0; i < 4; ++i)
#pragma unroll
      for (int j = 0; j < 4; ++j) acc[i][j] = MFMA16(a[i], bf[j], acc[i][j]);
    __syncthreads();
  }
#pragma unroll
  for (int i = 0; i < 4; ++i) {
#pragma unroll
    for (int j = 0; j < 4; ++j) {
      const int gn = bn + wc * 64 + j * 16 + r16;
      const float bb = bias[gn];
      const int h = gn >> 6, d = gn & 63;
      const int gm0 = bm + wr * 64 + i * 16 + g * 4;
      const int bb_ = gm0 >> 11, s0 = gm0 & (S_ - 1);
      const size_t bhbase = (size_t)(bb_ * H_ + h) * S_ * D_;
      if (z == 2) {
        half4v v4;
#pragma unroll
        for (int ii = 0; ii < 4; ++ii) v4[ii] = (_Float16)(acc[i][j][ii] + bb);
        *(half4v*)&Vth[bhbase + (size_t)(s0 >> 4) * (D_ * 16) + d * 16 + (s0 & 15)] = v4;
      } else if (z == 1) {
#pragma unroll
        for (int ii = 0; ii < 4; ++ii) {
          const int s = s0 + ii;
          Kh[bhbase + (size_t)(s >> 5) * 2048 + (d >> 4) * 512 + (s & 31) * 16 + (d & 15)] =
              (_Float16)(acc[i][j][ii] + bb);
        }
      } else {
#pragma unroll
        for (int ii = 0; ii < 4; ++ii)
          Qh[bhbase + (size_t)(s0 + ii) * D_ + d] = (_Float16)((acc[i][j][ii] + bb) * QSCALE);
      }
    }
  }
}

// ---------------- flash attention v8: R7 config + fused exp/pack/PV single pass ----------------
// 8 waves: wave = (khalf<<2)|qgroup. Each wave: 32 q rows, half the S loop.
// sc is read ONCE per element (no p write-back); exp2 of kc+1 overlaps PV MFMA of kc;
// cross-half lrun reduction deferred to after the S loop.
__global__ __launch_bounds__(512) void attn_kernel(
    const _Float16* __restrict__ Qh, const _Float16* __restrict__ Kh, const _Float16* __restrict__ Vth,
    const _Float16* __restrict__ maskH, _Float16* __restrict__ Oh) {
  __shared__ float mlds[4][64][36];  // [qgroup][lane][o32,m,l] from khalf=1 waves
  const int tid = threadIdx.x, lane = tid & 63, wid = tid >> 6;
  const int c = lane & 31, hi = lane >> 5;
  const int qg = wid & 3, kh = wid >> 2;
  const int b = blockIdx.z, h = blockIdx.y;
  const int qw = blockIdx.x * 128 + qg * 32;
  const size_t bh = (size_t)(b * H_ + h);
  const _Float16* Qb = Qh + bh * S_ * D_;
  const _Float16* Kb = Kh + bh * S_ * D_;
  const _Float16* Vb = Vth + bh * S_ * D_;
  const _Float16* mb = maskH + (size_t)b * S_;

  // Q B-frags (pre-scaled): col=q=c, kdim d = 16*kc + 8*hi + j
  half8v qb[4];
#pragma unroll
  for (int kc = 0; kc < 4; ++kc)
    qb[kc] = *(const half8v*)&Qb[(size_t)(qw + c) * D_ + 16 * kc + 8 * hi];

  half8v bone = {};
  if (hi == 0) bone[0] = (_Float16)1.0f;  // B[kdim=0][q]=1 for rank-1 mask MFMA
  const f32x16 fzero = {};

  f32x16 oacc[2] = {};  // out^T[d][q]
  float mrun = -1e30f, lrun = 0.f;  // lrun is PER-HALF partial until after the loop
  const int laneoff = c * 16 + 8 * hi;
  const int kb0 = kh * (S_ / 2);

  for (int kb = kb0; kb < kb0 + S_ / 2; kb += 64) {
    // ---- QK^T (swapped, log2 domain): sc[kt] = S^T[k][q] ----
    f32x16 sc[2];
#pragma unroll
    for (int kt = 0; kt < 2; ++kt) {
      half8v amask = {};
      _Float16 mv = mb[kb + 32 * kt + c];
      if (hi == 0) amask[0] = mv;
      const _Float16* kt_base = Kb + (size_t)((kb >> 5) + kt) * 2048 + laneoff;
      __builtin_amdgcn_s_setprio(1);
      f32x16 acc = MFMA32(amask, bone, fzero);
#pragma unroll
      for (int kc = 0; kc < 4; ++kc) {
        half8v ka = *(const half8v*)&kt_base[kc * 512];
        acc = MFMA32(ka, qb[kc], acc);
      }
      __builtin_amdgcn_s_setprio(0);
      sc[kt] = acc;
    }
    // ---- V preload (softmax-independent): issue now, consume in PV ----
    half8v va[8];
    {
      const _Float16* v_base = Vb + (size_t)(kb >> 4) * (D_ * 16) + laneoff;
#pragma unroll
      for (int kc = 0; kc < 4; ++kc) {
        va[2 * kc + 0] = *(const half8v*)&v_base[kc * (D_ * 16) + 0];
        va[2 * kc + 1] = *(const half8v*)&v_base[kc * (D_ * 16) + 512];
      }
    }
    // ---- row max: 4 parallel chains + cross-half ----
    float t0 = fmaxf(sc[0][0], sc[1][0]), t1 = fmaxf(sc[0][1], sc[1][1]);
    float t2 = fmaxf(sc[0][2], sc[1][2]), t3 = fmaxf(sc[0][3], sc[1][3]);
#pragma unroll
    for (int r = 4; r < 16; r += 4) {
      t0 = fmaxf(fmaxf(sc[0][r + 0], sc[1][r + 0]), t0);
      t1 = fmaxf(fmaxf(sc[0][r + 1], sc[1][r + 1]), t1);
      t2 = fmaxf(fmaxf(sc[0][r + 2], sc[1][r + 2]), t2);
      t3 = fmaxf(fmaxf(sc[0][r + 3], sc[1][r + 3]), t3);
    }
    float pmax = fmaxf(fmaxf(t0, t1), fmaxf(t2, t3));
    pmax = fmaxf(pmax, partner32(pmax, hi));
    // ---- defer-max rescale (T13, log2 units) ----
    if (__any(pmax > mrun + 11.0f)) {
      float mnew = fmaxf(mrun, pmax);
      float corr = __builtin_amdgcn_exp2f(mrun - mnew);
      mrun = mnew;
      lrun *= corr;
#pragma unroll
      for (int dt = 0; dt < 2; ++dt)
#pragma unroll
        for (int r = 0; r < 16; ++r) oacc[dt][r] *= corr;
    }
    // ---- FUSED: exp2 + pack + permlane + PV, one pass per kc ----
    float ps0 = 0.f, ps1 = 0.f;
#pragma unroll
    for (int kc = 0; kc < 4; ++kc) {
      const int kt = kc >> 1, bs = 8 * (kc & 1);
      float p0 = __builtin_amdgcn_exp2f(sc[kt][bs + 0] - mrun);
      float p1 = __builtin_amdgcn_exp2f(sc[kt][bs + 1] - mrun);
      float p2 = __builtin_amdgcn_exp2f(sc[kt][bs + 2] - mrun);
      float p3 = __builtin_amdgcn_exp2f(sc[kt][bs + 3] - mrun);
      float p4 = __builtin_amdgcn_exp2f(sc[kt][bs + 4] - mrun);
      float p5 = __builtin_amdgcn_exp2f(sc[kt][bs + 5] - mrun);
      float p6 = __builtin_amdgcn_exp2f(sc[kt][bs + 6] - mrun);
      float p7 = __builtin_amdgcn_exp2f(sc[kt][bs + 7] - mrun);
      ps0 += (p0 + p1) + (p2 + p3);
      ps1 += (p4 + p5) + (p6 + p7);
      unsigned uA = cvt_pk_u32(p0, p1);
      unsigned uB = cvt_pk_u32(p2, p3);
      unsigned uC = cvt_pk_u32(p4, p5);
      unsigned uD = cvt_pk_u32(p6, p7);
      unsigned w0, w1, w2, w3;
      pl32_swap(uA, uC, w0, w2);
      pl32_swap(uB, uD, w1, w3);
      uint4v u4 = {w0, w1, w2, w3};
      half8v pb = __builtin_bit_cast(half8v, u4);
      __builtin_amdgcn_s_setprio(1);
      oacc[0] = MFMA32(va[2 * kc + 0], pb, oacc[0]);
      oacc[1] = MFMA32(va[2 * kc + 1], pb, oacc[1]);
      __builtin_amdgcn_s_setprio(0);
    }
    lrun += ps0 + ps1;  // per-half partial; cross-half sum deferred
  }
  // ---- cross-half lrun reduction (once, not per tile) ----
  lrun += partner32(lrun, hi);
  // ---- k-split merge: khalf=1 publishes, khalf=0 merges + writes ----
  if (kh == 1) {
    float* p = &mlds[qg][lane][0];
#pragma unroll
    for (int dt = 0; dt < 2; ++dt)
#pragma unroll
      for (int rr = 0; rr < 4; ++rr) {
        float4 v4 = make_float4(oacc[dt][4 * rr], oacc[dt][4 * rr + 1],
                                oacc[dt][4 * rr + 2], oacc[dt][4 * rr + 3]);
        *(float4*)&p[dt * 16 + rr * 4] = v4;
      }
    p[32] = mrun;
    p[33] = lrun;
  }
  __syncthreads();
  if (kh == 0) {
    const float* p = &mlds[qg][lane][0];
    const float mB = p[32], lB = p[33];
    const float mS = fmaxf(mrun, mB);
    const float cA = __builtin_amdgcn_exp2f(mrun - mS);
    const float cB = __builtin_amdgcn_exp2f(mB - mS);
    const float inv = 1.0f / (lrun * cA + lB * cB);
    const float fA = cA * inv, fB = cB * inv;
    _Float16* orow = Oh + ((size_t)(b * S_ + qw + c)) * E_ + h * D_;
#pragma unroll
    for (int dt = 0; dt < 2; ++dt)
#pragma unroll
      for (int rr = 0; rr < 4; ++rr) {
        float4 vB = *(const float4*)&p[dt * 16 + rr * 4];
        half4v o4;
        o4[0] = (_Float16)(oacc[dt][4 * rr + 0] * fA + vB.x * fB);
        o4[1] = (_Float16)(oacc[dt][4 * rr + 1] * fA + vB.y * fB);
        o4[2] = (_Float16)(oacc[dt][4 * rr + 2] * fA + vB.z * fB);
        o4[3] = (_Float16)(oacc[dt][4 * rr + 3] * fA + vB.w * fB);
        *(half4v*)&orow[32 * dt + 8 * rr + 4 * hi] = o4;
      }
  }
}

// ---------------- output projection + abs(o*mask), fp32 out ----------------
__global__ __launch_bounds__(256) void oproj_gemm(
    const _Float16* __restrict__ Oh, const _Float16* __restrict__ wo, const float* __restrict__ bo,
    const float* __restrict__ qmask, float* __restrict__ out) {
  __shared__ _Float16 As[128 * 32];
  __shared__ _Float16 Bs[128 * 32];
  const int tid = threadIdx.x, lane = tid & 63, wid = tid >> 6;
  const int g = lane >> 4, r16 = lane & 15;
  const int bm = blockIdx.x * 128, bn = blockIdx.y * 128;
  const int wr = wid >> 1, wc = wid & 1;
  f32x4 acc[4][4] = {};
  for (int k0 = 0; k0 < E_; k0 += 32) {
    stage128x32(Oh + (size_t)bm * E_ + k0, E_, As, wid, lane);
    stage128x32(wo + (size_t)bn * E_ + k0, E_, Bs, wid, lane);
    __syncthreads();
    half8v a[4], bf[4];
#pragma unroll
    for (int i = 0; i < 4; ++i) a[i] = *(const half8v*)&As[(wr * 64 + i * 16 + r16) * 32 + g * 8];
#pragma unroll
    for (int i = 0; i < 4; ++i) bf[i] = *(const half8v*)&Bs[(wc * 64 + i * 16 + r16) * 32 + g * 8];
#pragma unroll
    for (int i = 0; i < 4; ++i)
#pragma unroll
      for (int j = 0; j < 4; ++j) acc[i][j] = MFMA16(a[i], bf[j], acc[i][j]);
    __syncthreads();
  }
#pragma unroll
  for (int i = 0; i < 4; ++i) {
#pragma unroll
    for (int j = 0; j < 4; ++j) {
      const int gn = bn + wc * 64 + j * 16 + r16;
      const float bb = bo[gn];
      const int gm0 = bm + wr * 64 + i * 16 + g * 4;
#pragma unroll
      for (int ii = 0; ii < 4; ++ii) {
        const int gm = gm0 + ii;
        const float y = acc[i][j][ii] + bb;
        out[(size_t)gm * E_ + gn] = fabsf(y * qmask[gm]);
      }
    }
  }
}

extern "C" void kernel_launch(void* const* d_in, const int* in_sizes, int n_in,
                              void* d_out, int out_size, void* d_ws, size_t ws_size,
                              hipStream_t stream) {
  const float* x = (const float*)d_in[0];
  const unsigned char* mask = (const unsigned char*)d_in[1];
  const float* WQ_w = (const float*)d_in[2];
  const float* WQ_b = (const float*)d_in[3];
  const float* WK_w = (const float*)d_in[4];
  const float* WK_b = (const float*)d_in[5];
  const float* WV_w = (const float*)d_in[6];
  const float* WV_b = (const float*)d_in[7];
  const float* WO_w = (const float*)d_in[8];
  const float* WO_b = (const float*)d_in[9];

  char* ws = (char*)d_ws;
  size_t off = 0;
  _Float16* xh  = (_Float16*)(ws + off); off += (size_t)MTOT * E_ * 2;  // reused as O after attn
  _Float16* wqh = (_Float16*)(ws + off); off += (size_t)E_ * E_ * 2;
  _Float16* wkh = (_Float16*)(ws + off); off += (size_t)E_ * E_ * 2;
  _Float16* wvh = (_Float16*)(ws + off); off += (size_t)E_ * E_ * 2;
  _Float16* woh = (_Float16*)(ws + off); off += (size_t)E_ * E_ * 2;
  _Float16* Qh  = (_Float16*)(ws + off); off += (size_t)MTOT * E_ * 2;
  _Float16* Kh  = (_Float16*)(ws + off); off += (size_t)MTOT * E_ * 2;
  _Float16* Vth = (_Float16*)(ws + off); off += (size_t)MTOT * E_ * 2;
  _Float16* maskHf = (_Float16*)(ws + off); off += (size_t)B_ * S_ * 2;
  float* qmaskf   = (float*)(ws + off); off += (size_t)B_ * S_ * 4;
  if (ws_size < off) return;

  const int NX = MTOT * E_;   // 8388608
  const int NW = E_ * E_;     // 1048576
  cvt_f32_f16<<<dim3(NX / 4 / 256), dim3(256), 0, stream>>>(x, xh, NX);
  cvt_f32_f16<<<dim3(NW / 4 / 256), dim3(256), 0, stream>>>(WQ_w, wqh, NW);
  cvt_f32_f16<<<dim3(NW / 4 / 256), dim3(256), 0, stream>>>(WK_w, wkh, NW);
  cvt_f32_f16<<<dim3(NW / 4 / 256), dim3(256), 0, stream>>>(WV_w, wvh, NW);
  cvt_f32_f16<<<dim3(NW / 4 / 256), dim3(256), 0, stream>>>(WO_w, woh, NW);
  mask_prep<<<dim3(1), dim3(1024), 0, stream>>>(mask, maskHf, qmaskf);
  qkv_gemm<<<dim3(MTOT / 128, E_ / 128, 3), dim3(256), 0, stream>>>(
      xh, wqh, wkh, wvh, WQ_b, WK_b, WV_b, Qh, Kh, Vth);
  attn_kernel<<<dim3(S_ / 128, H_, B_), dim3(512), 0, stream>>>(Qh, Kh, Vth, maskHf, xh);
  oproj_gemm<<<dim3(MTOT / 128, E_ / 128), dim3(256), 0, stream>>>(xh, woh, WO_b, qmaskf, (float*)d_out);
}

// Round 12
// 225.406 us; speedup vs baseline: 1.1553x; 1.1553x over previous
//
#include <hip/hip_runtime.h>
#include <math.h>

#define B_ 4
#define S_ 2048
#define E_ 1024
#define H_ 16
#define D_ 64
#define MTOT (B_*S_)

typedef _Float16 half8v __attribute__((ext_vector_type(8)));
typedef _Float16 half4v __attribute__((ext_vector_type(4)));
typedef float f32x4 __attribute__((ext_vector_type(4)));
typedef float f32x16 __attribute__((ext_vector_type(16)));
typedef unsigned uint4v __attribute__((ext_vector_type(4)));

typedef __attribute__((address_space(1))) const void gconst_void;
typedef __attribute__((address_space(3))) void lds_void;

#define MFMA16(a,b,c) __builtin_amdgcn_mfma_f32_16x16x32_f16((a),(b),(c),0,0,0)
#define MFMA32(a,b,c) __builtin_amdgcn_mfma_f32_32x32x16_f16((a),(b),(c),0,0,0)

#define QSCALE 0.18033688011112042f  /* 0.125 * log2(e): folded into Q at projection */

// pack two f32 -> u32 of 2 f16 (RTZ)
static __device__ __forceinline__ unsigned cvt_pk_u32(float a, float b) {
  return __builtin_bit_cast(unsigned, __builtin_amdgcn_cvt_pkrtz(a, b));
}

// {lo', hi'} = cross-half swap: lo' = {A.lo, B.lo}, hi' = {A.hi, B.hi}
#if __has_builtin(__builtin_amdgcn_permlane32_swap)
static __device__ __forceinline__ void pl32_swap(unsigned a, unsigned b,
                                                 unsigned& rlo, unsigned& rhi) {
  auto r = __builtin_amdgcn_permlane32_swap(a, b, false, false);
  rlo = r[0]; rhi = r[1];
}
#else
static __device__ __forceinline__ void pl32_swap(unsigned a, unsigned b,
                                                 unsigned& rlo, unsigned& rhi) {
  const int hi = (threadIdx.x & 63) >> 5;
  unsigned t = __shfl_xor(hi ? a : b, 32);
  rlo = hi ? t : a;
  rhi = hi ? b : t;
}
#endif

// partner-lane (lane^32) value of v
static __device__ __forceinline__ float partner32(float v, int hi) {
  unsigned u = __builtin_bit_cast(unsigned, v);
  unsigned lo_, hi_;
  pl32_swap(u, u, lo_, hi_);
  return __builtin_bit_cast(float, hi ? lo_ : hi_);
}

// ---------------- fp32 -> fp16 convert ----------------
__global__ __launch_bounds__(256) void cvt_f32_f16(const float* __restrict__ in,
                                                   _Float16* __restrict__ out, int n) {
  int i = (blockIdx.x * 256 + threadIdx.x) * 4;
  if (i >= n) return;
  float4 v = *(const float4*)(in + i);
  half4v o;
  o[0] = (_Float16)v.x; o[1] = (_Float16)v.y; o[2] = (_Float16)v.z; o[3] = (_Float16)v.w;
  *(half4v*)(out + i) = o;
}

// ---------------- mask prep (format auto-detect) ----------------
__global__ __launch_bounds__(1024) void mask_prep(const unsigned char* __restrict__ mraw,
                                                  _Float16* __restrict__ maskH,
                                                  float* __restrict__ qmask) {
  __shared__ int flags[2];
  const int tid = threadIdx.x;
  if (tid < 2) flags[tid] = 1;
  __syncthreads();
  const unsigned int* w = (const unsigned int*)mraw;
  for (int i = tid; i < 2048; i += 1024) {
    unsigned int v = w[i];
    if (!(v == 0u || v == 1u)) flags[0] = 0;
    if (!(v == 0u || v == 0x3f800000u)) flags[1] = 0;
  }
  __syncthreads();
  const int is_i32 = flags[0], is_f32 = flags[1];
  for (int i = tid; i < B_ * S_; i += 1024) {
    int mv;
    if (is_i32)      mv = ((const int*)mraw)[i];
    else if (is_f32) mv = (((const unsigned int*)mraw)[i] != 0u);
    else             mv = (mraw[i] != 0);
    maskH[i]  = mv ? (_Float16)0.0f : (_Float16)(-60000.0f);
    qmask[i]  = mv ? 1.0f : 0.0f;
  }
}

// ---------------- GEMM staging: 128 rows x 32 f16 cols -> LDS (linear) ----------------
__device__ __forceinline__ void stage128x32(const _Float16* __restrict__ g, int ld,
                                            _Float16* lds, int wid, int lane) {
#pragma unroll
  for (int j = 0; j < 2; ++j) {
    const int c = j * 256 + wid * 64 + lane;
    const _Float16* src = g + (size_t)(c >> 2) * ld + (c & 3) * 8;
    _Float16* dst = lds + (size_t)(j * 256 + wid * 64) * 8;
    __builtin_amdgcn_global_load_lds((gconst_void*)src, (lds_void*)dst, 16, 0, 0);
  }
}

// ---------------- QKV projection GEMM ----------------
// Q stored row-major (B,H,S,D), PRE-SCALED by QSCALE (softmax in log2 domain).
// K stored FRAGMENT-LINEAR: Kf[bh][s>>5][d>>4][s&31][d&15]
// V stored FRAGMENT-LINEAR: Vf[bh][s>>4][d][s&15]
__global__ __launch_bounds__(256) void qkv_gemm(
    const _Float16* __restrict__ xh,
    const _Float16* __restrict__ wq, const _Float16* __restrict__ wk, const _Float16* __restrict__ wv,
    const float* __restrict__ bq, const float* __restrict__ bkp, const float* __restrict__ bvp,
    _Float16* __restrict__ Qh, _Float16* __restrict__ Kh, _Float16* __restrict__ Vth) {
  __shared__ _Float16 As[128 * 32];
  __shared__ _Float16 Bs[128 * 32];
  const int tid = threadIdx.x, lane = tid & 63, wid = tid >> 6;
  const int g = lane >> 4, r16 = lane & 15;
  const int bm = blockIdx.x * 128, bn = blockIdx.y * 128;
  const int z = blockIdx.z;
  const _Float16* w = (z == 0) ? wq : (z == 1) ? wk : wv;
  const float* bias = (z == 0) ? bq : (z == 1) ? bkp : bvp;
  const int wr = wid >> 1, wc = wid & 1;
  f32x4 acc[4][4] = {};
  for (int k0 = 0; k0 < E_; k0 += 32) {
    stage128x32(xh + (size_t)bm * E_ + k0, E_, As, wid, lane);
    stage128x32(w + (size_t)bn * E_ + k0, E_, Bs, wid, lane);
    __syncthreads();
    half8v a[4], bf[4];
#pragma unroll
    for (int i = 0; i < 4; ++i) a[i] = *(const half8v*)&As[(wr * 64 + i * 16 + r16) * 32 + g * 8];
#pragma unroll
    for (int i = 0; i < 4; ++i) bf[i] = *(const half8v*)&Bs[(wc * 64 + i * 16 + r16) * 32 + g * 8];
#pragma unroll
    for (int i = 0; i < 4; ++i)
#pragma unroll
      for (int j = 0; j < 4; ++j) acc[i][j] = MFMA16(a[i], bf[j], acc[i][j]);
    __syncthreads();
  }
#pragma unroll
  for (int i = 0; i < 4; ++i) {
#pragma unroll
    for (int j = 0; j < 4; ++j) {
      const int gn = bn + wc * 64 + j * 16 + r16;
      const float bb = bias[gn];
      const int h = gn >> 6, d = gn & 63;
      const int gm0 = bm + wr * 64 + i * 16 + g * 4;
      const int bb_ = gm0 >> 11, s0 = gm0 & (S_ - 1);
      const size_t bhbase = (size_t)(bb_ * H_ + h) * S_ * D_;
      if (z == 2) {
        half4v v4;
#pragma unroll
        for (int ii = 0; ii < 4; ++ii) v4[ii] = (_Float16)(acc[i][j][ii] + bb);
        *(half4v*)&Vth[bhbase + (size_t)(s0 >> 4) * (D_ * 16) + d * 16 + (s0 & 15)] = v4;
      } else if (z == 1) {
#pragma unroll
        for (int ii = 0; ii < 4; ++ii) {
          const int s = s0 + ii;
          Kh[bhbase + (size_t)(s >> 5) * 2048 + (d >> 4) * 512 + (s & 31) * 16 + (d & 15)] =
              (_Float16)(acc[i][j][ii] + bb);
        }
      } else {
#pragma unroll
        for (int ii = 0; ii < 4; ++ii)
          Qh[bhbase + (size_t)(s0 + ii) * D_ + d] = (_Float16)((acc[i][j][ii] + bb) * QSCALE);
      }
    }
  }
}

// ---------------- flash attention v9: KVBLK=32 (half softmax state), k-split x2 ----------------
// 8 waves: wave = (khalf<<2)|qgroup. Each wave: 32 q rows, half the S loop, 32 k per iter.
// sc = f32x16 only -> softmax state fits arch VGPRs at 64-reg occupancy sweet spot.
__global__ __launch_bounds__(512) void attn_kernel(
    const _Float16* __restrict__ Qh, const _Float16* __restrict__ Kh, const _Float16* __restrict__ Vth,
    const _Float16* __restrict__ maskH, _Float16* __restrict__ Oh) {
  __shared__ float mlds[4][64][36];  // [qgroup][lane][o32,m,l] from khalf=1 waves
  const int tid = threadIdx.x, lane = tid & 63, wid = tid >> 6;
  const int c = lane & 31, hi = lane >> 5;
  const int qg = wid & 3, kh = wid >> 2;
  const int b = blockIdx.z, h = blockIdx.y;
  const int qw = blockIdx.x * 128 + qg * 32;
  const size_t bh = (size_t)(b * H_ + h);
  const _Float16* Qb = Qh + bh * S_ * D_;
  const _Float16* Kb = Kh + bh * S_ * D_;
  const _Float16* Vb = Vth + bh * S_ * D_;
  const _Float16* mb = maskH + (size_t)b * S_;

  // Q B-frags (pre-scaled): col=q=c, kdim d = 16*kc + 8*hi + j
  half8v qb[4];
#pragma unroll
  for (int kc = 0; kc < 4; ++kc)
    qb[kc] = *(const half8v*)&Qb[(size_t)(qw + c) * D_ + 16 * kc + 8 * hi];

  half8v bone = {};
  if (hi == 0) bone[0] = (_Float16)1.0f;  // B[kdim=0][q]=1 for rank-1 mask MFMA
  const f32x16 fzero = {};

  f32x16 oacc[2] = {};  // out^T[d][q]
  float mrun = -1e30f, lrun = 0.f;  // lrun is PER-HALF partial until after the loop
  const int laneoff = c * 16 + 8 * hi;
  const int kb0 = kh * (S_ / 2);

  for (int kb = kb0; kb < kb0 + S_ / 2; kb += 32) {
    // ---- QK^T (swapped, log2 domain): sc = S^T[k=kb+row][q], 32 k-values ----
    half8v amask = {};
    _Float16 mv = mb[kb + c];
    if (hi == 0) amask[0] = mv;
    const _Float16* kt_base = Kb + (size_t)(kb >> 5) * 2048 + laneoff;
    __builtin_amdgcn_s_setprio(1);
    f32x16 sc = MFMA32(amask, bone, fzero);
#pragma unroll
    for (int kc = 0; kc < 4; ++kc) {
      half8v ka = *(const half8v*)&kt_base[kc * 512];
      sc = MFMA32(ka, qb[kc], sc);
    }
    __builtin_amdgcn_s_setprio(0);
    // ---- V fragments for this 32-k slab (2 sub-slices x 2 d-tiles) ----
    const _Float16* v_base = Vb + (size_t)(kb >> 4) * (D_ * 16) + laneoff;
    half8v va00 = *(const half8v*)&v_base[0];
    half8v va01 = *(const half8v*)&v_base[512];
    half8v va10 = *(const half8v*)&v_base[1024];
    half8v va11 = *(const half8v*)&v_base[1024 + 512];
    // ---- row max: 4 parallel chains + cross-half ----
    float t0 = fmaxf(sc[0], sc[4]), t1 = fmaxf(sc[1], sc[5]);
    float t2 = fmaxf(sc[2], sc[6]), t3 = fmaxf(sc[3], sc[7]);
    t0 = fmaxf(fmaxf(sc[8], sc[12]), t0);
    t1 = fmaxf(fmaxf(sc[9], sc[13]), t1);
    t2 = fmaxf(fmaxf(sc[10], sc[14]), t2);
    t3 = fmaxf(fmaxf(sc[11], sc[15]), t3);
    float pmax = fmaxf(fmaxf(t0, t1), fmaxf(t2, t3));
    pmax = fmaxf(pmax, partner32(pmax, hi));
    // ---- defer-max rescale (T13, log2 units) ----
    if (__any(pmax > mrun + 11.0f)) {
      float mnew = fmaxf(mrun, pmax);
      float corr = __builtin_amdgcn_exp2f(mrun - mnew);
      mrun = mnew;
      lrun *= corr;
#pragma unroll
      for (int dt = 0; dt < 2; ++dt)
#pragma unroll
        for (int r = 0; r < 16; ++r) oacc[dt][r] *= corr;
    }
    // ---- FUSED: exp2 + pack + permlane + PV, one pass per 16-k sub-slice ----
    float ps0 = 0.f, ps1 = 0.f;
#pragma unroll
    for (int sl = 0; sl < 2; ++sl) {
      const int bs = 8 * sl;
      float p0 = __builtin_amdgcn_exp2f(sc[bs + 0] - mrun);
      float p1 = __builtin_amdgcn_exp2f(sc[bs + 1] - mrun);
      float p2 = __builtin_amdgcn_exp2f(sc[bs + 2] - mrun);
      float p3 = __builtin_amdgcn_exp2f(sc[bs + 3] - mrun);
      float p4 = __builtin_amdgcn_exp2f(sc[bs + 4] - mrun);
      float p5 = __builtin_amdgcn_exp2f(sc[bs + 5] - mrun);
      float p6 = __builtin_amdgcn_exp2f(sc[bs + 6] - mrun);
      float p7 = __builtin_amdgcn_exp2f(sc[bs + 7] - mrun);
      ps0 += (p0 + p1) + (p2 + p3);
      ps1 += (p4 + p5) + (p6 + p7);
      unsigned uA = cvt_pk_u32(p0, p1);
      unsigned uB = cvt_pk_u32(p2, p3);
      unsigned uC = cvt_pk_u32(p4, p5);
      unsigned uD = cvt_pk_u32(p6, p7);
      unsigned w0, w1, w2, w3;
      pl32_swap(uA, uC, w0, w2);
      pl32_swap(uB, uD, w1, w3);
      uint4v u4 = {w0, w1, w2, w3};
      half8v pb = __builtin_bit_cast(half8v, u4);
      __builtin_amdgcn_s_setprio(1);
      oacc[0] = MFMA32(sl ? va10 : va00, pb, oacc[0]);
      oacc[1] = MFMA32(sl ? va11 : va01, pb, oacc[1]);
      __builtin_amdgcn_s_setprio(0);
    }
    lrun += ps0 + ps1;  // per-half partial; cross-half sum deferred
  }
  // ---- cross-half lrun reduction (once, not per tile) ----
  lrun += partner32(lrun, hi);
  // ---- k-split merge: khalf=1 publishes, khalf=0 merges + writes ----
  if (kh == 1) {
    float* p = &mlds[qg][lane][0];
#pragma unroll
    for (int dt = 0; dt < 2; ++dt)
#pragma unroll
      for (int rr = 0; rr < 4; ++rr) {
        float4 v4 = make_float4(oacc[dt][4 * rr], oacc[dt][4 * rr + 1],
                                oacc[dt][4 * rr + 2], oacc[dt][4 * rr + 3]);
        *(float4*)&p[dt * 16 + rr * 4] = v4;
      }
    p[32] = mrun;
    p[33] = lrun;
  }
  __syncthreads();
  if (kh == 0) {
    const float* p = &mlds[qg][lane][0];
    const float mB = p[32], lB = p[33];
    const float mS = fmaxf(mrun, mB);
    const float cA = __builtin_amdgcn_exp2f(mrun - mS);
    const float cB = __builtin_amdgcn_exp2f(mB - mS);
    const float inv = 1.0f / (lrun * cA + lB * cB);
    const float fA = cA * inv, fB = cB * inv;
    _Float16* orow = Oh + ((size_t)(b * S_ + qw + c)) * E_ + h * D_;
#pragma unroll
    for (int dt = 0; dt < 2; ++dt)
#pragma unroll
      for (int rr = 0; rr < 4; ++rr) {
        float4 vB = *(const float4*)&p[dt * 16 + rr * 4];
        half4v o4;
        o4[0] = (_Float16)(oacc[dt][4 * rr + 0] * fA + vB.x * fB);
        o4[1] = (_Float16)(oacc[dt][4 * rr + 1] * fA + vB.y * fB);
        o4[2] = (_Float16)(oacc[dt][4 * rr + 2] * fA + vB.z * fB);
        o4[3] = (_Float16)(oacc[dt][4 * rr + 3] * fA + vB.w * fB);
        *(half4v*)&orow[32 * dt + 8 * rr + 4 * hi] = o4;
      }
  }
}

// ---------------- output projection + abs(o*mask), fp32 out ----------------
__global__ __launch_bounds__(256) void oproj_gemm(
    const _Float16* __restrict__ Oh, const _Float16* __restrict__ wo, const float* __restrict__ bo,
    const float* __restrict__ qmask, float* __restrict__ out) {
  __shared__ _Float16 As[128 * 32];
  __shared__ _Float16 Bs[128 * 32];
  const int tid = threadIdx.x, lane = tid & 63, wid = tid >> 6;
  const int g = lane >> 4, r16 = lane & 15;
  const int bm = blockIdx.x * 128, bn = blockIdx.y * 128;
  const int wr = wid >> 1, wc = wid & 1;
  f32x4 acc[4][4] = {};
  for (int k0 = 0; k0 < E_; k0 += 32) {
    stage128x32(Oh + (size_t)bm * E_ + k0, E_, As, wid, lane);
    stage128x32(wo + (size_t)bn * E_ + k0, E_, Bs, wid, lane);
    __syncthreads();
    half8v a[4], bf[4];
#pragma unroll
    for (int i = 0; i < 4; ++i) a[i] = *(const half8v*)&As[(wr * 64 + i * 16 + r16) * 32 + g * 8];
#pragma unroll
    for (int i = 0; i < 4; ++i) bf[i] = *(const half8v*)&Bs[(wc * 64 + i * 16 + r16) * 32 + g * 8];
#pragma unroll
    for (int i = 0; i < 4; ++i)
#pragma unroll
      for (int j = 0; j < 4; ++j) acc[i][j] = MFMA16(a[i], bf[j], acc[i][j]);
    __syncthreads();
  }
#pragma unroll
  for (int i = 0; i < 4; ++i) {
#pragma unroll
    for (int j = 0; j < 4; ++j) {
      const int gn = bn + wc * 64 + j * 16 + r16;
      const float bb = bo[gn];
      const int gm0 = bm + wr * 64 + i * 16 + g * 4;
#pragma unroll
      for (int ii = 0; ii < 4; ++ii) {
        const int gm = gm0 + ii;
        const float y = acc[i][j][ii] + bb;
        out[(size_t)gm * E_ + gn] = fabsf(y * qmask[gm]);
      }
    }
  }
}

extern "C" void kernel_launch(void* const* d_in, const int* in_sizes, int n_in,
                              void* d_out, int out_size, void* d_ws, size_t ws_size,
                              hipStream_t stream) {
  const float* x = (const float*)d_in[0];
  const unsigned char* mask = (const unsigned char*)d_in[1];
  const float* WQ_w = (const float*)d_in[2];
  const float* WQ_b = (const float*)d_in[3];
  const float* WK_w = (const float*)d_in[4];
  const float* WK_b = (const float*)d_in[5];
  const float* WV_w = (const float*)d_in[6];
  const float* WV_b = (const float*)d_in[7];
  const float* WO_w = (const float*)d_in[8];
  const float* WO_b = (const float*)d_in[9];

  char* ws = (char*)d_ws;
  size_t off = 0;
  _Float16* xh  = (_Float16*)(ws + off); off += (size_t)MTOT * E_ * 2;  // reused as O after attn
  _Float16* wqh = (_Float16*)(ws + off); off += (size_t)E_ * E_ * 2;
  _Float16* wkh = (_Float16*)(ws + off); off += (size_t)E_ * E_ * 2;
  _Float16* wvh = (_Float16*)(ws + off); off += (size_t)E_ * E_ * 2;
  _Float16* woh = (_Float16*)(ws + off); off += (size_t)E_ * E_ * 2;
  _Float16* Qh  = (_Float16*)(ws + off); off += (size_t)MTOT * E_ * 2;
  _Float16* Kh  = (_Float16*)(ws + off); off += (size_t)MTOT * E_ * 2;
  _Float16* Vth = (_Float16*)(ws + off); off += (size_t)MTOT * E_ * 2;
  _Float16* maskHf = (_Float16*)(ws + off); off += (size_t)B_ * S_ * 2;
  float* qmaskf   = (float*)(ws + off); off += (size_t)B_ * S_ * 4;
  if (ws_size < off) return;

  const int NX = MTOT * E_;   // 8388608
  const int NW = E_ * E_;     // 1048576
  cvt_f32_f16<<<dim3(NX / 4 / 256), dim3(256), 0, stream>>>(x, xh, NX);
  cvt_f32_f16<<<dim3(NW / 4 / 256), dim3(256), 0, stream>>>(WQ_w, wqh, NW);
  cvt_f32_f16<<<dim3(NW / 4 / 256), dim3(256), 0, stream>>>(WK_w, wkh, NW);
  cvt_f32_f16<<<dim3(NW / 4 / 256), dim3(256), 0, stream>>>(WV_w, wvh, NW);
  cvt_f32_f16<<<dim3(NW / 4 / 256), dim3(256), 0, stream>>>(WO_w, woh, NW);
  mask_prep<<<dim3(1), dim3(1024), 0, stream>>>(mask, maskHf, qmaskf);
  qkv_gemm<<<dim3(MTOT / 128, E_ / 128, 3), dim3(256), 0, stream>>>(
      xh, wqh, wkh, wvh, WQ_b, WK_b, WV_b, Qh, Kh, Vth);
  attn_kernel<<<dim3(S_ / 128, H_, B_), dim3(512), 0, stream>>>(Qh, Kh, Vth, maskHf, xh);
  oproj_gemm<<<dim3(MTOT / 128, E_ / 128), dim3(256), 0, stream>>>(xh, woh, WO_b, qmaskf, (float*)d_out);
}

// Round 13
// 216.480 us; speedup vs baseline: 1.2029x; 1.0412x over previous
//
#include <hip/hip_runtime.h>
#include <math.h>

#define B_ 4
#define S_ 2048
#define E_ 1024
#define H_ 16
#define D_ 64
#define MTOT (B_*S_)

typedef _Float16 half8v __attribute__((ext_vector_type(8)));
typedef _Float16 half4v __attribute__((ext_vector_type(4)));
typedef float f32x4 __attribute__((ext_vector_type(4)));
typedef float f32x16 __attribute__((ext_vector_type(16)));
typedef unsigned uint4v __attribute__((ext_vector_type(4)));

typedef __attribute__((address_space(1))) const void gconst_void;
typedef __attribute__((address_space(3))) void lds_void;

#define MFMA16(a,b,c) __builtin_amdgcn_mfma_f32_16x16x32_f16((a),(b),(c),0,0,0)
#define MFMA32(a,b,c) __builtin_amdgcn_mfma_f32_32x32x16_f16((a),(b),(c),0,0,0)

#define QSCALE 0.18033688011112042f  /* 0.125 * log2(e): folded into Q at projection */

// pack two f32 -> u32 of 2 f16 (RTZ)
static __device__ __forceinline__ unsigned cvt_pk_u32(float a, float b) {
  return __builtin_bit_cast(unsigned, __builtin_amdgcn_cvt_pkrtz(a, b));
}

// {lo', hi'} = cross-half swap: lo' = {A.lo, B.lo}, hi' = {A.hi, B.hi}
#if __has_builtin(__builtin_amdgcn_permlane32_swap)
static __device__ __forceinline__ void pl32_swap(unsigned a, unsigned b,
                                                 unsigned& rlo, unsigned& rhi) {
  auto r = __builtin_amdgcn_permlane32_swap(a, b, false, false);
  rlo = r[0]; rhi = r[1];
}
#else
static __device__ __forceinline__ void pl32_swap(unsigned a, unsigned b,
                                                 unsigned& rlo, unsigned& rhi) {
  const int hi = (threadIdx.x & 63) >> 5;
  unsigned t = __shfl_xor(hi ? a : b, 32);
  rlo = hi ? t : a;
  rhi = hi ? b : t;
}
#endif

// partner-lane (lane^32) value of v
static __device__ __forceinline__ float partner32(float v, int hi) {
  unsigned u = __builtin_bit_cast(unsigned, v);
  unsigned lo_, hi_;
  pl32_swap(u, u, lo_, hi_);
  return __builtin_bit_cast(float, hi ? lo_ : hi_);
}

// ---------------- fp32 -> fp16 convert (x) ----------------
__global__ __launch_bounds__(256) void cvt_f32_f16(const float* __restrict__ in,
                                                   _Float16* __restrict__ out, int n) {
  int i = (blockIdx.x * 256 + threadIdx.x) * 4;
  if (i >= n) return;
  float4 v = *(const float4*)(in + i);
  half4v o;
  o[0] = (_Float16)v.x; o[1] = (_Float16)v.y; o[2] = (_Float16)v.z; o[3] = (_Float16)v.w;
  *(half4v*)(out + i) = o;
}

// ---------------- fp32 -> fp16 convert, 4 weight matrices in one launch ----------------
__global__ __launch_bounds__(256) void cvt_w4(const float* __restrict__ w0, const float* __restrict__ w1,
                                              const float* __restrict__ w2, const float* __restrict__ w3,
                                              _Float16* __restrict__ o0, _Float16* __restrict__ o1,
                                              _Float16* __restrict__ o2, _Float16* __restrict__ o3) {
  const int z = blockIdx.y;
  const float* in = (z == 0) ? w0 : (z == 1) ? w1 : (z == 2) ? w2 : w3;
  _Float16* out = (z == 0) ? o0 : (z == 1) ? o1 : (z == 2) ? o2 : o3;
  int i = (blockIdx.x * 256 + threadIdx.x) * 4;
  float4 v = *(const float4*)(in + i);
  half4v o;
  o[0] = (_Float16)v.x; o[1] = (_Float16)v.y; o[2] = (_Float16)v.z; o[3] = (_Float16)v.w;
  *(half4v*)(out + i) = o;
}

// ---------------- mask prep (format auto-detect) ----------------
__global__ __launch_bounds__(1024) void mask_prep(const unsigned char* __restrict__ mraw,
                                                  _Float16* __restrict__ maskH,
                                                  float* __restrict__ qmask) {
  __shared__ int flags[2];
  const int tid = threadIdx.x;
  if (tid < 2) flags[tid] = 1;
  __syncthreads();
  const unsigned int* w = (const unsigned int*)mraw;
  for (int i = tid; i < 2048; i += 1024) {
    unsigned int v = w[i];
    if (!(v == 0u || v == 1u)) flags[0] = 0;
    if (!(v == 0u || v == 0x3f800000u)) flags[1] = 0;
  }
  __syncthreads();
  const int is_i32 = flags[0], is_f32 = flags[1];
  for (int i = tid; i < B_ * S_; i += 1024) {
    int mv;
    if (is_i32)      mv = ((const int*)mraw)[i];
    else if (is_f32) mv = (((const unsigned int*)mraw)[i] != 0u);
    else             mv = (mraw[i] != 0);
    maskH[i]  = mv ? (_Float16)0.0f : (_Float16)(-60000.0f);
    qmask[i]  = mv ? 1.0f : 0.0f;
  }
}

// ---------------- GEMM staging: 128 rows x 32 f16 cols -> LDS (linear) ----------------
__device__ __forceinline__ void stage128x32(const _Float16* __restrict__ g, int ld,
                                            _Float16* lds, int wid, int lane) {
#pragma unroll
  for (int j = 0; j < 2; ++j) {
    const int c = j * 256 + wid * 64 + lane;
    const _Float16* src = g + (size_t)(c >> 2) * ld + (c & 3) * 8;
    _Float16* dst = lds + (size_t)(j * 256 + wid * 64) * 8;
    __builtin_amdgcn_global_load_lds((gconst_void*)src, (lds_void*)dst, 16, 0, 0);
  }
}

// ---------------- QKV projection GEMM ----------------
// Q stored row-major (B,H,S,D), PRE-SCALED by QSCALE (softmax in log2 domain).
// K stored FRAGMENT-LINEAR: Kf[bh][s>>5][d>>4][s&31][d&15]
// V stored FRAGMENT-LINEAR: Vf[bh][s>>4][d][s&15]
__global__ __launch_bounds__(256) void qkv_gemm(
    const _Float16* __restrict__ xh,
    const _Float16* __restrict__ wq, const _Float16* __restrict__ wk, const _Float16* __restrict__ wv,
    const float* __restrict__ bq, const float* __restrict__ bkp, const float* __restrict__ bvp,
    _Float16* __restrict__ Qh, _Float16* __restrict__ Kh, _Float16* __restrict__ Vth) {
  __shared__ _Float16 As[128 * 32];
  __shared__ _Float16 Bs[128 * 32];
  const int tid = threadIdx.x, lane = tid & 63, wid = tid >> 6;
  const int g = lane >> 4, r16 = lane & 15;
  const int bm = blockIdx.x * 128, bn = blockIdx.y * 128;
  const int z = blockIdx.z;
  const _Float16* w = (z == 0) ? wq : (z == 1) ? wk : wv;
  const float* bias = (z == 0) ? bq : (z == 1) ? bkp : bvp;
  const int wr = wid >> 1, wc = wid & 1;
  f32x4 acc[4][4] = {};
  for (int k0 = 0; k0 < E_; k0 += 32) {
    stage128x32(xh + (size_t)bm * E_ + k0, E_, As, wid, lane);
    stage128x32(w + (size_t)bn * E_ + k0, E_, Bs, wid, lane);
    __syncthreads();
    half8v a[4], bf[4];
#pragma unroll
    for (int i = 0; i < 4; ++i) a[i] = *(const half8v*)&As[(wr * 64 + i * 16 + r16) * 32 + g * 8];
#pragma unroll
    for (int i = 0; i < 4; ++i) bf[i] = *(const half8v*)&Bs[(wc * 64 + i * 16 + r16) * 32 + g * 8];
#pragma unroll
    for (int i = 0; i < 4; ++i)
#pragma unroll
      for (int j = 0; j < 4; ++j) acc[i][j] = MFMA16(a[i], bf[j], acc[i][j]);
    __syncthreads();
  }
#pragma unroll
  for (int i = 0; i < 4; ++i) {
#pragma unroll
    for (int j = 0; j < 4; ++j) {
      const int gn = bn + wc * 64 + j * 16 + r16;
      const float bb = bias[gn];
      const int h = gn >> 6, d = gn & 63;
      const int gm0 = bm + wr * 64 + i * 16 + g * 4;
      const int bb_ = gm0 >> 11, s0 = gm0 & (S_ - 1);
      const size_t bhbase = (size_t)(bb_ * H_ + h) * S_ * D_;
      if (z == 2) {
        half4v v4;
#pragma unroll
        for (int ii = 0; ii < 4; ++ii) v4[ii] = (_Float16)(acc[i][j][ii] + bb);
        *(half4v*)&Vth[bhbase + (size_t)(s0 >> 4) * (D_ * 16) + d * 16 + (s0 & 15)] = v4;
      } else if (z == 1) {
#pragma unroll
        for (int ii = 0; ii < 4; ++ii) {
          const int s = s0 + ii;
          Kh[bhbase + (size_t)(s >> 5) * 2048 + (d >> 4) * 512 + (s & 31) * 16 + (d & 15)] =
              (_Float16)(acc[i][j][ii] + bb);
        }
      } else {
#pragma unroll
        for (int ii = 0; ii < 4; ++ii)
          Qh[bhbase + (size_t)(s0 + ii) * D_ + d] = (_Float16)((acc[i][j][ii] + bb) * QSCALE);
      }
    }
  }
}

// ---------------- flash attention v10: KVBLK=32, k-split x2, XCD-swizzled grid ----------------
// 1D grid, id = (hb&7) + 8*(t + 16*(hb>>3)): all 16 q-tiles of one head land on one XCD
// (8 heads/XCD = 4MB K/V = one L2). 8 waves: wave = (khalf<<2)|qgroup.
__global__ __launch_bounds__(512) void attn_kernel(
    const _Float16* __restrict__ Qh, const _Float16* __restrict__ Kh, const _Float16* __restrict__ Vth,
    const _Float16* __restrict__ maskH, _Float16* __restrict__ Oh) {
  __shared__ float mlds[4][64][36];  // [qgroup][lane][o32,m,l] from khalf=1 waves
  const int tid = threadIdx.x, lane = tid & 63, wid = tid >> 6;
  const int c = lane & 31, hi = lane >> 5;
  const int qg = wid & 3, kh = wid >> 2;
  // XCD-aware decode: slot = id&7 keeps same-head blocks on one XCD
  const int id = blockIdx.x;
  const int slot = id & 7, rest = id >> 3;
  const int t = rest & 15, hbh = rest >> 4;
  const int hb = hbh * 8 + slot;
  const int b = hb >> 4, h = hb & 15;
  const int qw = t * 128 + qg * 32;
  const size_t bh = (size_t)(b * H_ + h);
  const _Float16* Qb = Qh + bh * S_ * D_;
  const _Float16* Kb = Kh + bh * S_ * D_;
  const _Float16* Vb = Vth + bh * S_ * D_;
  const _Float16* mb = maskH + (size_t)b * S_;

  // Q B-frags (pre-scaled): col=q=c, kdim d = 16*kc + 8*hi + j
  half8v qb[4];
#pragma unroll
  for (int kc = 0; kc < 4; ++kc)
    qb[kc] = *(const half8v*)&Qb[(size_t)(qw + c) * D_ + 16 * kc + 8 * hi];

  half8v bone = {};
  if (hi == 0) bone[0] = (_Float16)1.0f;  // B[kdim=0][q]=1 for rank-1 mask MFMA
  const f32x16 fzero = {};

  f32x16 oacc[2] = {};  // out^T[d][q]
  float mrun = -1e30f, lrun = 0.f;  // lrun is PER-HALF partial until after the loop
  const int laneoff = c * 16 + 8 * hi;
  const int kb0 = kh * (S_ / 2);

  for (int kb = kb0; kb < kb0 + S_ / 2; kb += 32) {
    // ---- QK^T (swapped, log2 domain): sc = S^T[k=kb+row][q], 32 k-values ----
    half8v amask = {};
    _Float16 mv = mb[kb + c];
    if (hi == 0) amask[0] = mv;
    const _Float16* kt_base = Kb + (size_t)(kb >> 5) * 2048 + laneoff;
    __builtin_amdgcn_s_setprio(1);
    f32x16 sc = MFMA32(amask, bone, fzero);
#pragma unroll
    for (int kc = 0; kc < 4; ++kc) {
      half8v ka = *(const half8v*)&kt_base[kc * 512];
      sc = MFMA32(ka, qb[kc], sc);
    }
    __builtin_amdgcn_s_setprio(0);
    // ---- V fragments for this 32-k slab (2 sub-slices x 2 d-tiles) ----
    const _Float16* v_base = Vb + (size_t)(kb >> 4) * (D_ * 16) + laneoff;
    half8v va00 = *(const half8v*)&v_base[0];
    half8v va01 = *(const half8v*)&v_base[512];
    half8v va10 = *(const half8v*)&v_base[1024];
    half8v va11 = *(const half8v*)&v_base[1024 + 512];
    // ---- row max: 4 parallel chains + cross-half ----
    float t0 = fmaxf(sc[0], sc[4]), t1 = fmaxf(sc[1], sc[5]);
    float t2 = fmaxf(sc[2], sc[6]), t3 = fmaxf(sc[3], sc[7]);
    t0 = fmaxf(fmaxf(sc[8], sc[12]), t0);
    t1 = fmaxf(fmaxf(sc[9], sc[13]), t1);
    t2 = fmaxf(fmaxf(sc[10], sc[14]), t2);
    t3 = fmaxf(fmaxf(sc[11], sc[15]), t3);
    float pmax = fmaxf(fmaxf(t0, t1), fmaxf(t2, t3));
    pmax = fmaxf(pmax, partner32(pmax, hi));
    // ---- defer-max rescale (T13, log2 units) ----
    if (__any(pmax > mrun + 11.0f)) {
      float mnew = fmaxf(mrun, pmax);
      float corr = __builtin_amdgcn_exp2f(mrun - mnew);
      mrun = mnew;
      lrun *= corr;
#pragma unroll
      for (int dt = 0; dt < 2; ++dt)
#pragma unroll
        for (int r = 0; r < 16; ++r) oacc[dt][r] *= corr;
    }
    // ---- FUSED: exp2 + pack + permlane + PV, one pass per 16-k sub-slice ----
    float ps0 = 0.f, ps1 = 0.f;
#pragma unroll
    for (int sl = 0; sl < 2; ++sl) {
      const int bs = 8 * sl;
      float p0 = __builtin_amdgcn_exp2f(sc[bs + 0] - mrun);
      float p1 = __builtin_amdgcn_exp2f(sc[bs + 1] - mrun);
      float p2 = __builtin_amdgcn_exp2f(sc[bs + 2] - mrun);
      float p3 = __builtin_amdgcn_exp2f(sc[bs + 3] - mrun);
      float p4 = __builtin_amdgcn_exp2f(sc[bs + 4] - mrun);
      float p5 = __builtin_amdgcn_exp2f(sc[bs + 5] - mrun);
      float p6 = __builtin_amdgcn_exp2f(sc[bs + 6] - mrun);
      float p7 = __builtin_amdgcn_exp2f(sc[bs + 7] - mrun);
      ps0 += (p0 + p1) + (p2 + p3);
      ps1 += (p4 + p5) + (p6 + p7);
      unsigned uA = cvt_pk_u32(p0, p1);
      unsigned uB = cvt_pk_u32(p2, p3);
      unsigned uC = cvt_pk_u32(p4, p5);
      unsigned uD = cvt_pk_u32(p6, p7);
      unsigned w0, w1, w2, w3;
      pl32_swap(uA, uC, w0, w2);
      pl32_swap(uB, uD, w1, w3);
      uint4v u4 = {w0, w1, w2, w3};
      half8v pb = __builtin_bit_cast(half8v, u4);
      __builtin_amdgcn_s_setprio(1);
      oacc[0] = MFMA32(sl ? va10 : va00, pb, oacc[0]);
      oacc[1] = MFMA32(sl ? va11 : va01, pb, oacc[1]);
      __builtin_amdgcn_s_setprio(0);
    }
    lrun += ps0 + ps1;  // per-half partial; cross-half sum deferred
  }
  // ---- cross-half lrun reduction (once, not per tile) ----
  lrun += partner32(lrun, hi);
  // ---- k-split merge: khalf=1 publishes, khalf=0 merges + writes ----
  if (kh == 1) {
    float* p = &mlds[qg][lane][0];
#pragma unroll
    for (int dt = 0; dt < 2; ++dt)
#pragma unroll
      for (int rr = 0; rr < 4; ++rr) {
        float4 v4 = make_float4(oacc[dt][4 * rr], oacc[dt][4 * rr + 1],
                                oacc[dt][4 * rr + 2], oacc[dt][4 * rr + 3]);
        *(float4*)&p[dt * 16 + rr * 4] = v4;
      }
    p[32] = mrun;
    p[33] = lrun;
  }
  __syncthreads();
  if (kh == 0) {
    const float* p = &mlds[qg][lane][0];
    const float mB = p[32], lB = p[33];
    const float mS = fmaxf(mrun, mB);
    const float cA = __builtin_amdgcn_exp2f(mrun - mS);
    const float cB = __builtin_amdgcn_exp2f(mB - mS);
    const float inv = 1.0f / (lrun * cA + lB * cB);
    const float fA = cA * inv, fB = cB * inv;
    _Float16* orow = Oh + ((size_t)(b * S_ + qw + c)) * E_ + h * D_;
#pragma unroll
    for (int dt = 0; dt < 2; ++dt)
#pragma unroll
      for (int rr = 0; rr < 4; ++rr) {
        float4 vB = *(const float4*)&p[dt * 16 + rr * 4];
        half4v o4;
        o4[0] = (_Float16)(oacc[dt][4 * rr + 0] * fA + vB.x * fB);
        o4[1] = (_Float16)(oacc[dt][4 * rr + 1] * fA + vB.y * fB);
        o4[2] = (_Float16)(oacc[dt][4 * rr + 2] * fA + vB.z * fB);
        o4[3] = (_Float16)(oacc[dt][4 * rr + 3] * fA + vB.w * fB);
        *(half4v*)&orow[32 * dt + 8 * rr + 4 * hi] = o4;
      }
  }
}

// ---------------- output projection + abs(o*mask), fp32 out ----------------
__global__ __launch_bounds__(256) void oproj_gemm(
    const _Float16* __restrict__ Oh, const _Float16* __restrict__ wo, const float* __restrict__ bo,
    const float* __restrict__ qmask, float* __restrict__ out) {
  __shared__ _Float16 As[128 * 32];
  __shared__ _Float16 Bs[128 * 32];
  const int tid = threadIdx.x, lane = tid & 63, wid = tid >> 6;
  const int g = lane >> 4, r16 = lane & 15;
  const int bm = blockIdx.x * 128, bn = blockIdx.y * 128;
  const int wr = wid >> 1, wc = wid & 1;
  f32x4 acc[4][4] = {};
  for (int k0 = 0; k0 < E_; k0 += 32) {
    stage128x32(Oh + (size_t)bm * E_ + k0, E_, As, wid, lane);
    stage128x32(wo + (size_t)bn * E_ + k0, E_, Bs, wid, lane);
    __syncthreads();
    half8v a[4], bf[4];
#pragma unroll
    for (int i = 0; i < 4; ++i) a[i] = *(const half8v*)&As[(wr * 64 + i * 16 + r16) * 32 + g * 8];
#pragma unroll
    for (int i = 0; i < 4; ++i) bf[i] = *(const half8v*)&Bs[(wc * 64 + i * 16 + r16) * 32 + g * 8];
#pragma unroll
    for (int i = 0; i < 4; ++i)
#pragma unroll
      for (int j = 0; j < 4; ++j) acc[i][j] = MFMA16(a[i], bf[j], acc[i][j]);
    __syncthreads();
  }
#pragma unroll
  for (int i = 0; i < 4; ++i) {
#pragma unroll
    for (int j = 0; j < 4; ++j) {
      const int gn = bn + wc * 64 + j * 16 + r16;
      const float bb = bo[gn];
      const int gm0 = bm + wr * 64 + i * 16 + g * 4;
#pragma unroll
      for (int ii = 0; ii < 4; ++ii) {
        const int gm = gm0 + ii;
        const float y = acc[i][j][ii] + bb;
        out[(size_t)gm * E_ + gn] = fabsf(y * qmask[gm]);
      }
    }
  }
}

extern "C" void kernel_launch(void* const* d_in, const int* in_sizes, int n_in,
                              void* d_out, int out_size, void* d_ws, size_t ws_size,
                              hipStream_t stream) {
  const float* x = (const float*)d_in[0];
  const unsigned char* mask = (const unsigned char*)d_in[1];
  const float* WQ_w = (const float*)d_in[2];
  const float* WQ_b = (const float*)d_in[3];
  const float* WK_w = (const float*)d_in[4];
  const float* WK_b = (const float*)d_in[5];
  const float* WV_w = (const float*)d_in[6];
  const float* WV_b = (const float*)d_in[7];
  const float* WO_w = (const float*)d_in[8];
  const float* WO_b = (const float*)d_in[9];

  char* ws = (char*)d_ws;
  size_t off = 0;
  _Float16* xh  = (_Float16*)(ws + off); off += (size_t)MTOT * E_ * 2;  // reused as O after attn
  _Float16* wqh = (_Float16*)(ws + off); off += (size_t)E_ * E_ * 2;
  _Float16* wkh = (_Float16*)(ws + off); off += (size_t)E_ * E_ * 2;
  _Float16* wvh = (_Float16*)(ws + off); off += (size_t)E_ * E_ * 2;
  _Float16* woh = (_Float16*)(ws + off); off += (size_t)E_ * E_ * 2;
  _Float16* Qh  = (_Float16*)(ws + off); off += (size_t)MTOT * E_ * 2;
  _Float16* Kh  = (_Float16*)(ws + off); off += (size_t)MTOT * E_ * 2;
  _Float16* Vth = (_Float16*)(ws + off); off += (size_t)MTOT * E_ * 2;
  _Float16* maskHf = (_Float16*)(ws + off); off += (size_t)B_ * S_ * 2;
  float* qmaskf   = (float*)(ws + off); off += (size_t)B_ * S_ * 4;
  if (ws_size < off) return;

  const int NX = MTOT * E_;   // 8388608
  const int NW = E_ * E_;     // 1048576
  cvt_f32_f16<<<dim3(NX / 4 / 256), dim3(256), 0, stream>>>(x, xh, NX);
  cvt_w4<<<dim3(NW / 4 / 256, 4), dim3(256), 0, stream>>>(WQ_w, WK_w, WV_w, WO_w,
                                                          wqh, wkh, wvh, woh);
  mask_prep<<<dim3(1), dim3(1024), 0, stream>>>(mask, maskHf, qmaskf);
  qkv_gemm<<<dim3(MTOT / 128, E_ / 128, 3), dim3(256), 0, stream>>>(
      xh, wqh, wkh, wvh, WQ_b, WK_b, WV_b, Qh, Kh, Vth);
  attn_kernel<<<dim3((S_ / 128) * H_ * B_), dim3(512), 0, stream>>>(Qh, Kh, Vth, maskHf, xh);
  oproj_gemm<<<dim3(MTOT / 128, E_ / 128), dim3(256), 0, stream>>>(xh, woh, WO_b, qmaskf, (float*)d_out);
}

// Round 14
// 207.841 us; speedup vs baseline: 1.2529x; 1.0416x over previous
//
#include <hip/hip_runtime.h>
#include <math.h>

#define B_ 4
#define S_ 2048
#define E_ 1024
#define H_ 16
#define D_ 64
#define MTOT (B_*S_)

typedef _Float16 half8v __attribute__((ext_vector_type(8)));
typedef _Float16 half4v __attribute__((ext_vector_type(4)));
typedef float f32x4 __attribute__((ext_vector_type(4)));
typedef float f32x16 __attribute__((ext_vector_type(16)));
typedef unsigned uint4v __attribute__((ext_vector_type(4)));

typedef __attribute__((address_space(1))) const void gconst_void;
typedef __attribute__((address_space(3))) void lds_void;

#define MFMA16(a,b,c) __builtin_amdgcn_mfma_f32_16x16x32_f16((a),(b),(c),0,0,0)
#define MFMA32(a,b,c) __builtin_amdgcn_mfma_f32_32x32x16_f16((a),(b),(c),0,0,0)

#define QSCALE 0.18033688011112042f  /* 0.125 * log2(e): folded into Q at projection */

// pack two f32 -> u32 of 2 f16 (RTZ)
static __device__ __forceinline__ unsigned cvt_pk_u32(float a, float b) {
  return __builtin_bit_cast(unsigned, __builtin_amdgcn_cvt_pkrtz(a, b));
}

// {lo', hi'} = cross-half swap: lo' = {A.lo, B.lo}, hi' = {A.hi, B.hi}
#if __has_builtin(__builtin_amdgcn_permlane32_swap)
static __device__ __forceinline__ void pl32_swap(unsigned a, unsigned b,
                                                 unsigned& rlo, unsigned& rhi) {
  auto r = __builtin_amdgcn_permlane32_swap(a, b, false, false);
  rlo = r[0]; rhi = r[1];
}
#else
static __device__ __forceinline__ void pl32_swap(unsigned a, unsigned b,
                                                 unsigned& rlo, unsigned& rhi) {
  const int hi = (threadIdx.x & 63) >> 5;
  unsigned t = __shfl_xor(hi ? a : b, 32);
  rlo = hi ? t : a;
  rhi = hi ? b : t;
}
#endif

// partner-lane (lane^32) value of v
static __device__ __forceinline__ float partner32(float v, int hi) {
  unsigned u = __builtin_bit_cast(unsigned, v);
  unsigned lo_, hi_;
  pl32_swap(u, u, lo_, hi_);
  return __builtin_bit_cast(float, hi ? lo_ : hi_);
}

// ---------------- fp32 -> fp16 convert (x) ----------------
__global__ __launch_bounds__(256) void cvt_f32_f16(const float* __restrict__ in,
                                                   _Float16* __restrict__ out, int n) {
  int i = (blockIdx.x * 256 + threadIdx.x) * 4;
  if (i >= n) return;
  float4 v = *(const float4*)(in + i);
  half4v o;
  o[0] = (_Float16)v.x; o[1] = (_Float16)v.y; o[2] = (_Float16)v.z; o[3] = (_Float16)v.w;
  *(half4v*)(out + i) = o;
}

// ---------------- fp32 -> fp16 convert, 4 weight matrices in one launch ----------------
__global__ __launch_bounds__(256) void cvt_w4(const float* __restrict__ w0, const float* __restrict__ w1,
                                              const float* __restrict__ w2, const float* __restrict__ w3,
                                              _Float16* __restrict__ o0, _Float16* __restrict__ o1,
                                              _Float16* __restrict__ o2, _Float16* __restrict__ o3) {
  const int z = blockIdx.y;
  const float* in = (z == 0) ? w0 : (z == 1) ? w1 : (z == 2) ? w2 : w3;
  _Float16* out = (z == 0) ? o0 : (z == 1) ? o1 : (z == 2) ? o2 : o3;
  int i = (blockIdx.x * 256 + threadIdx.x) * 4;
  float4 v = *(const float4*)(in + i);
  half4v o;
  o[0] = (_Float16)v.x; o[1] = (_Float16)v.y; o[2] = (_Float16)v.z; o[3] = (_Float16)v.w;
  *(half4v*)(out + i) = o;
}

// ---------------- mask prep (format auto-detect, multi-block) ----------------
__global__ __launch_bounds__(1024) void mask_prep(const unsigned char* __restrict__ mraw,
                                                  _Float16* __restrict__ maskH,
                                                  float* __restrict__ qmask) {
  __shared__ int flags[2];
  const int tid = threadIdx.x;
  if (tid < 2) flags[tid] = 1;
  __syncthreads();
  const unsigned int* w = (const unsigned int*)mraw;
  for (int i = tid; i < 2048; i += 1024) {  // redundant per-block detect scan (read-only)
    unsigned int v = w[i];
    if (!(v == 0u || v == 1u)) flags[0] = 0;
    if (!(v == 0u || v == 0x3f800000u)) flags[1] = 0;
  }
  __syncthreads();
  const int is_i32 = flags[0], is_f32 = flags[1];
  for (int i = blockIdx.x * 1024 + tid; i < B_ * S_; i += gridDim.x * 1024) {
    int mv;
    if (is_i32)      mv = ((const int*)mraw)[i];
    else if (is_f32) mv = (((const unsigned int*)mraw)[i] != 0u);
    else             mv = (mraw[i] != 0);
    maskH[i]  = mv ? (_Float16)0.0f : (_Float16)(-60000.0f);
    qmask[i]  = mv ? 1.0f : 0.0f;
  }
}

// ---------------- GEMM staging: 128 rows x 32 f16 cols -> LDS (linear) ----------------
__device__ __forceinline__ void stage128x32(const _Float16* __restrict__ g, int ld,
                                            _Float16* lds, int wid, int lane) {
#pragma unroll
  for (int j = 0; j < 2; ++j) {
    const int c = j * 256 + wid * 64 + lane;
    const _Float16* src = g + (size_t)(c >> 2) * ld + (c & 3) * 8;
    _Float16* dst = lds + (size_t)(j * 256 + wid * 64) * 8;
    __builtin_amdgcn_global_load_lds((gconst_void*)src, (lds_void*)dst, 16, 0, 0);
  }
}

// ---------------- QKV projection GEMM ----------------
// Q stored row-major (B,H,S,D), PRE-SCALED by QSCALE (softmax in log2 domain).
// K stored FRAGMENT-LINEAR: Kf[bh][s>>5][d>>4][s&31][d&15]
// V stored FRAGMENT-LINEAR: Vf[bh][s>>4][d][s&15]
__global__ __launch_bounds__(256) void qkv_gemm(
    const _Float16* __restrict__ xh,
    const _Float16* __restrict__ wq, const _Float16* __restrict__ wk, const _Float16* __restrict__ wv,
    const float* __restrict__ bq, const float* __restrict__ bkp, const float* __restrict__ bvp,
    _Float16* __restrict__ Qh, _Float16* __restrict__ Kh, _Float16* __restrict__ Vth) {
  __shared__ _Float16 As[128 * 32];
  __shared__ _Float16 Bs[128 * 32];
  const int tid = threadIdx.x, lane = tid & 63, wid = tid >> 6;
  const int g = lane >> 4, r16 = lane & 15;
  const int bm = blockIdx.x * 128, bn = blockIdx.y * 128;
  const int z = blockIdx.z;
  const _Float16* w = (z == 0) ? wq : (z == 1) ? wk : wv;
  const float* bias = (z == 0) ? bq : (z == 1) ? bkp : bvp;
  const int wr = wid >> 1, wc = wid & 1;
  f32x4 acc[4][4] = {};
  for (int k0 = 0; k0 < E_; k0 += 32) {
    stage128x32(xh + (size_t)bm * E_ + k0, E_, As, wid, lane);
    stage128x32(w + (size_t)bn * E_ + k0, E_, Bs, wid, lane);
    __syncthreads();
    half8v a[4], bf[4];
#pragma unroll
    for (int i = 0; i < 4; ++i) a[i] = *(const half8v*)&As[(wr * 64 + i * 16 + r16) * 32 + g * 8];
#pragma unroll
    for (int i = 0; i < 4; ++i) bf[i] = *(const half8v*)&Bs[(wc * 64 + i * 16 + r16) * 32 + g * 8];
#pragma unroll
    for (int i = 0; i < 4; ++i)
#pragma unroll
      for (int j = 0; j < 4; ++j) acc[i][j] = MFMA16(a[i], bf[j], acc[i][j]);
    __syncthreads();
  }
#pragma unroll
  for (int i = 0; i < 4; ++i) {
#pragma unroll
    for (int j = 0; j < 4; ++j) {
      const int gn = bn + wc * 64 + j * 16 + r16;
      const float bb = bias[gn];
      const int h = gn >> 6, d = gn & 63;
      const int gm0 = bm + wr * 64 + i * 16 + g * 4;
      const int bb_ = gm0 >> 11, s0 = gm0 & (S_ - 1);
      const size_t bhbase = (size_t)(bb_ * H_ + h) * S_ * D_;
      if (z == 2) {
        half4v v4;
#pragma unroll
        for (int ii = 0; ii < 4; ++ii) v4[ii] = (_Float16)(acc[i][j][ii] + bb);
        *(half4v*)&Vth[bhbase + (size_t)(s0 >> 4) * (D_ * 16) + d * 16 + (s0 & 15)] = v4;
      } else if (z == 1) {
#pragma unroll
        for (int ii = 0; ii < 4; ++ii) {
          const int s = s0 + ii;
          Kh[bhbase + (size_t)(s >> 5) * 2048 + (d >> 4) * 512 + (s & 31) * 16 + (d & 15)] =
              (_Float16)(acc[i][j][ii] + bb);
        }
      } else {
#pragma unroll
        for (int ii = 0; ii < 4; ++ii)
          Qh[bhbase + (size_t)(s0 + ii) * D_ + d] = (_Float16)((acc[i][j][ii] + bb) * QSCALE);
      }
    }
  }
}

// ---------------- flash attention v11: pipelined K/mask prefetch, LDS mask ----------------
// KVBLK=32, k-split x2, XCD-swizzled 1D grid. 8 waves: wave = (khalf<<2)|qgroup.
// K-frags + mask prefetched one iter ahead (register-resident at QK^T time);
// mask row staged in LDS (aliased into merge buffer).
__global__ __launch_bounds__(512) void attn_kernel(
    const _Float16* __restrict__ Qh, const _Float16* __restrict__ Kh, const _Float16* __restrict__ Vth,
    const _Float16* __restrict__ maskH, _Float16* __restrict__ Oh) {
  __shared__ float mlds[4][64][36];  // merge buffer; first 4KB aliased as mask row during loop
  _Float16* smask = (_Float16*)&mlds[0][0][0];
  const int tid = threadIdx.x, lane = tid & 63, wid = tid >> 6;
  const int c = lane & 31, hi = lane >> 5;
  const int qg = wid & 3, kh = wid >> 2;
  // XCD-aware decode: slot = id&7 keeps same-head blocks on one XCD
  const int id = blockIdx.x;
  const int slot = id & 7, rest = id >> 3;
  const int t = rest & 15, hbh = rest >> 4;
  const int hb = hbh * 8 + slot;
  const int b = hb >> 4, h = hb & 15;
  const int qw = t * 128 + qg * 32;
  const size_t bh = (size_t)(b * H_ + h);
  const _Float16* Qb = Qh + bh * S_ * D_;
  const _Float16* Kb = Kh + bh * S_ * D_;
  const _Float16* Vb = Vth + bh * S_ * D_;

  // stage this batch's mask row (2048 f16 = 4KB) into LDS
  *((half4v*)smask + tid) = *((const half4v*)(maskH + (size_t)b * S_) + tid);

  // Q B-frags (pre-scaled): col=q=c, kdim d = 16*kc + 8*hi + j
  half8v qb[4];
#pragma unroll
  for (int kc = 0; kc < 4; ++kc)
    qb[kc] = *(const half8v*)&Qb[(size_t)(qw + c) * D_ + 16 * kc + 8 * hi];

  half8v bone = {};
  if (hi == 0) bone[0] = (_Float16)1.0f;  // B[kdim=0][q]=1 for rank-1 mask MFMA
  const f32x16 fzero = {};

  f32x16 oacc[2] = {};  // out^T[d][q]
  float mrun = -1e30f, lrun = 0.f;  // lrun is PER-HALF partial until after the loop
  const int laneoff = c * 16 + 8 * hi;
  const int kb0 = kh * (S_ / 2);

  __syncthreads();  // mask staged

  // prefetch iter-0 K frags + mask value
  half8v kaf[4];
  {
    const _Float16* ktb = Kb + (size_t)(kb0 >> 5) * 2048 + laneoff;
#pragma unroll
    for (int kc = 0; kc < 4; ++kc) kaf[kc] = *(const half8v*)&ktb[kc * 512];
  }
  _Float16 mv = smask[kb0 + c];

  for (int kb = kb0; kb < kb0 + S_ / 2; kb += 32) {
    // ---- QK^T from register-resident fragments ----
    half8v amask = {};
    if (hi == 0) amask[0] = mv;
    __builtin_amdgcn_s_setprio(1);
    f32x16 sc = MFMA32(amask, bone, fzero);
    sc = MFMA32(kaf[0], qb[0], sc);
    sc = MFMA32(kaf[1], qb[1], sc);
    sc = MFMA32(kaf[2], qb[2], sc);
    sc = MFMA32(kaf[3], qb[3], sc);
    __builtin_amdgcn_s_setprio(0);
    // ---- prefetch next-iter K frags + mask; V frags for this iter ----
    const int kbn = (kb + 32 < kb0 + S_ / 2) ? kb + 32 : kb0;  // branchless (last-iter load harmless)
    {
      const _Float16* ktb = Kb + (size_t)(kbn >> 5) * 2048 + laneoff;
#pragma unroll
      for (int kc = 0; kc < 4; ++kc) kaf[kc] = *(const half8v*)&ktb[kc * 512];
    }
    mv = smask[kbn + c];
    const _Float16* v_base = Vb + (size_t)(kb >> 4) * (D_ * 16) + laneoff;
    half8v va00 = *(const half8v*)&v_base[0];
    half8v va01 = *(const half8v*)&v_base[512];
    half8v va10 = *(const half8v*)&v_base[1024];
    half8v va11 = *(const half8v*)&v_base[1024 + 512];
    // ---- row max: 4 parallel chains + cross-half ----
    float t0 = fmaxf(sc[0], sc[4]), t1 = fmaxf(sc[1], sc[5]);
    float t2 = fmaxf(sc[2], sc[6]), t3 = fmaxf(sc[3], sc[7]);
    t0 = fmaxf(fmaxf(sc[8], sc[12]), t0);
    t1 = fmaxf(fmaxf(sc[9], sc[13]), t1);
    t2 = fmaxf(fmaxf(sc[10], sc[14]), t2);
    t3 = fmaxf(fmaxf(sc[11], sc[15]), t3);
    float pmax = fmaxf(fmaxf(t0, t1), fmaxf(t2, t3));
    pmax = fmaxf(pmax, partner32(pmax, hi));
    // ---- defer-max rescale (T13, log2 units) ----
    if (__any(pmax > mrun + 11.0f)) {
      float mnew = fmaxf(mrun, pmax);
      float corr = __builtin_amdgcn_exp2f(mrun - mnew);
      mrun = mnew;
      lrun *= corr;
#pragma unroll
      for (int dt = 0; dt < 2; ++dt)
#pragma unroll
        for (int r = 0; r < 16; ++r) oacc[dt][r] *= corr;
    }
    // ---- FUSED: exp2 + pack + permlane + PV, one pass per 16-k sub-slice ----
    float ps0 = 0.f, ps1 = 0.f;
#pragma unroll
    for (int sl = 0; sl < 2; ++sl) {
      const int bs = 8 * sl;
      float p0 = __builtin_amdgcn_exp2f(sc[bs + 0] - mrun);
      float p1 = __builtin_amdgcn_exp2f(sc[bs + 1] - mrun);
      float p2 = __builtin_amdgcn_exp2f(sc[bs + 2] - mrun);
      float p3 = __builtin_amdgcn_exp2f(sc[bs + 3] - mrun);
      float p4 = __builtin_amdgcn_exp2f(sc[bs + 4] - mrun);
      float p5 = __builtin_amdgcn_exp2f(sc[bs + 5] - mrun);
      float p6 = __builtin_amdgcn_exp2f(sc[bs + 6] - mrun);
      float p7 = __builtin_amdgcn_exp2f(sc[bs + 7] - mrun);
      ps0 += (p0 + p1) + (p2 + p3);
      ps1 += (p4 + p5) + (p6 + p7);
      unsigned uA = cvt_pk_u32(p0, p1);
      unsigned uB = cvt_pk_u32(p2, p3);
      unsigned uC = cvt_pk_u32(p4, p5);
      unsigned uD = cvt_pk_u32(p6, p7);
      unsigned w0, w1, w2, w3;
      pl32_swap(uA, uC, w0, w2);
      pl32_swap(uB, uD, w1, w3);
      uint4v u4 = {w0, w1, w2, w3};
      half8v pb = __builtin_bit_cast(half8v, u4);
      __builtin_amdgcn_s_setprio(1);
      oacc[0] = MFMA32(sl ? va10 : va00, pb, oacc[0]);
      oacc[1] = MFMA32(sl ? va11 : va01, pb, oacc[1]);
      __builtin_amdgcn_s_setprio(0);
    }
    lrun += ps0 + ps1;  // per-half partial; cross-half sum deferred
  }
  // ---- cross-half lrun reduction (once, not per tile) ----
  lrun += partner32(lrun, hi);
  // ---- k-split merge (mask alias dead from here; barrier protects it) ----
  __syncthreads();
  if (kh == 1) {
    float* p = &mlds[qg][lane][0];
#pragma unroll
    for (int dt = 0; dt < 2; ++dt)
#pragma unroll
      for (int rr = 0; rr < 4; ++rr) {
        float4 v4 = make_float4(oacc[dt][4 * rr], oacc[dt][4 * rr + 1],
                                oacc[dt][4 * rr + 2], oacc[dt][4 * rr + 3]);
        *(float4*)&p[dt * 16 + rr * 4] = v4;
      }
    p[32] = mrun;
    p[33] = lrun;
  }
  __syncthreads();
  if (kh == 0) {
    const float* p = &mlds[qg][lane][0];
    const float mB = p[32], lB = p[33];
    const float mS = fmaxf(mrun, mB);
    const float cA = __builtin_amdgcn_exp2f(mrun - mS);
    const float cB = __builtin_amdgcn_exp2f(mB - mS);
    const float inv = 1.0f / (lrun * cA + lB * cB);
    const float fA = cA * inv, fB = cB * inv;
    _Float16* orow = Oh + ((size_t)(b * S_ + qw + c)) * E_ + h * D_;
#pragma unroll
    for (int dt = 0; dt < 2; ++dt)
#pragma unroll
      for (int rr = 0; rr < 4; ++rr) {
        float4 vB = *(const float4*)&p[dt * 16 + rr * 4];
        half4v o4;
        o4[0] = (_Float16)(oacc[dt][4 * rr + 0] * fA + vB.x * fB);
        o4[1] = (_Float16)(oacc[dt][4 * rr + 1] * fA + vB.y * fB);
        o4[2] = (_Float16)(oacc[dt][4 * rr + 2] * fA + vB.z * fB);
        o4[3] = (_Float16)(oacc[dt][4 * rr + 3] * fA + vB.w * fB);
        *(half4v*)&orow[32 * dt + 8 * rr + 4 * hi] = o4;
      }
  }
}

// ---------------- output projection + abs(o*mask), fp32 out ----------------
__global__ __launch_bounds__(256) void oproj_gemm(
    const _Float16* __restrict__ Oh, const _Float16* __restrict__ wo, const float* __restrict__ bo,
    const float* __restrict__ qmask, float* __restrict__ out) {
  __shared__ _Float16 As[128 * 32];
  __shared__ _Float16 Bs[128 * 32];
  const int tid = threadIdx.x, lane = tid & 63, wid = tid >> 6;
  const int g = lane >> 4, r16 = lane & 15;
  const int bm = blockIdx.x * 128, bn = blockIdx.y * 128;
  const int wr = wid >> 1, wc = wid & 1;
  f32x4 acc[4][4] = {};
  for (int k0 = 0; k0 < E_; k0 += 32) {
    stage128x32(Oh + (size_t)bm * E_ + k0, E_, As, wid, lane);
    stage128x32(wo + (size_t)bn * E_ + k0, E_, Bs, wid, lane);
    __syncthreads();
    half8v a[4], bf[4];
#pragma unroll
    for (int i = 0; i < 4; ++i) a[i] = *(const half8v*)&As[(wr * 64 + i * 16 + r16) * 32 + g * 8];
#pragma unroll
    for (int i = 0; i < 4; ++i) bf[i] = *(const half8v*)&Bs[(wc * 64 + i * 16 + r16) * 32 + g * 8];
#pragma unroll
    for (int i = 0; i < 4; ++i)
#pragma unroll
      for (int j = 0; j < 4; ++j) acc[i][j] = MFMA16(a[i], bf[j], acc[i][j]);
    __syncthreads();
  }
#pragma unroll
  for (int i = 0; i < 4; ++i) {
#pragma unroll
    for (int j = 0; j < 4; ++j) {
      const int gn = bn + wc * 64 + j * 16 + r16;
      const float bb = bo[gn];
      const int gm0 = bm + wr * 64 + i * 16 + g * 4;
#pragma unroll
      for (int ii = 0; ii < 4; ++ii) {
        const int gm = gm0 + ii;
        const float y = acc[i][j][ii] + bb;
        out[(size_t)gm * E_ + gn] = fabsf(y * qmask[gm]);
      }
    }
  }
}

extern "C" void kernel_launch(void* const* d_in, const int* in_sizes, int n_in,
                              void* d_out, int out_size, void* d_ws, size_t ws_size,
                              hipStream_t stream) {
  const float* x = (const float*)d_in[0];
  const unsigned char* mask = (const unsigned char*)d_in[1];
  const float* WQ_w = (const float*)d_in[2];
  const float* WQ_b = (const float*)d_in[3];
  const float* WK_w = (const float*)d_in[4];
  const float* WK_b = (const float*)d_in[5];
  const float* WV_w = (const float*)d_in[6];
  const float* WV_b = (const float*)d_in[7];
  const float* WO_w = (const float*)d_in[8];
  const float* WO_b = (const float*)d_in[9];

  char* ws = (char*)d_ws;
  size_t off = 0;
  _Float16* xh  = (_Float16*)(ws + off); off += (size_t)MTOT * E_ * 2;  // reused as O after attn
  _Float16* wqh = (_Float16*)(ws + off); off += (size_t)E_ * E_ * 2;
  _Float16* wkh = (_Float16*)(ws + off); off += (size_t)E_ * E_ * 2;
  _Float16* wvh = (_Float16*)(ws + off); off += (size_t)E_ * E_ * 2;
  _Float16* woh = (_Float16*)(ws + off); off += (size_t)E_ * E_ * 2;
  _Float16* Qh  = (_Float16*)(ws + off); off += (size_t)MTOT * E_ * 2;
  _Float16* Kh  = (_Float16*)(ws + off); off += (size_t)MTOT * E_ * 2;
  _Float16* Vth = (_Float16*)(ws + off); off += (size_t)MTOT * E_ * 2;
  _Float16* maskHf = (_Float16*)(ws + off); off += (size_t)B_ * S_ * 2;
  float* qmaskf   = (float*)(ws + off); off += (size_t)B_ * S_ * 4;
  if (ws_size < off) return;

  const int NX = MTOT * E_;   // 8388608
  const int NW = E_ * E_;     // 1048576
  cvt_f32_f16<<<dim3(NX / 4 / 256), dim3(256), 0, stream>>>(x, xh, NX);
  cvt_w4<<<dim3(NW / 4 / 256, 4), dim3(256), 0, stream>>>(WQ_w, WK_w, WV_w, WO_w,
                                                          wqh, wkh, wvh, woh);
  mask_prep<<<dim3(8), dim3(1024), 0, stream>>>(mask, maskHf, qmaskf);
  qkv_gemm<<<dim3(MTOT / 128, E_ / 128, 3), dim3(256), 0, stream>>>(
      xh, wqh, wkh, wvh, WQ_b, WK_b, WV_b, Qh, Kh, Vth);
  attn_kernel<<<dim3((S_ / 128) * H_ * B_), dim3(512), 0, stream>>>(Qh, Kh, Vth, maskHf, xh);
  oproj_gemm<<<dim3(MTOT / 128, E_ / 128), dim3(256), 0, stream>>>(xh, woh, WO_b, qmaskf, (float*)d_out);
}

// Round 15
// 170.095 us; speedup vs baseline: 1.5309x; 1.2219x over previous
//
#include <hip/hip_runtime.h>
#include <math.h>

#define B_ 4
#define S_ 2048
#define E_ 1024
#define H_ 16
#define D_ 64
#define MTOT (B_*S_)

typedef _Float16 half8v __attribute__((ext_vector_type(8)));
typedef _Float16 half4v __attribute__((ext_vector_type(4)));
typedef float f32x4 __attribute__((ext_vector_type(4)));
typedef float f32x16 __attribute__((ext_vector_type(16)));
typedef unsigned uint4v __attribute__((ext_vector_type(4)));

typedef __attribute__((address_space(1))) const void gconst_void;
typedef __attribute__((address_space(3))) void lds_void;

#define MFMA16(a,b,c) __builtin_amdgcn_mfma_f32_16x16x32_f16((a),(b),(c),0,0,0)
#define MFMA32(a,b,c) __builtin_amdgcn_mfma_f32_32x32x16_f16((a),(b),(c),0,0,0)

#define QSCALE 0.18033688011112042f  /* 0.125 * log2(e): folded into Q at projection */

static __device__ __forceinline__ unsigned cvt_pk_u32(float a, float b) {
  return __builtin_bit_cast(unsigned, __builtin_amdgcn_cvt_pkrtz(a, b));
}

#if __has_builtin(__builtin_amdgcn_permlane32_swap)
static __device__ __forceinline__ void pl32_swap(unsigned a, unsigned b,
                                                 unsigned& rlo, unsigned& rhi) {
  auto r = __builtin_amdgcn_permlane32_swap(a, b, false, false);
  rlo = r[0]; rhi = r[1];
}
#else
static __device__ __forceinline__ void pl32_swap(unsigned a, unsigned b,
                                                 unsigned& rlo, unsigned& rhi) {
  const int hi = (threadIdx.x & 63) >> 5;
  unsigned t = __shfl_xor(hi ? a : b, 32);
  rlo = hi ? t : a;
  rhi = hi ? b : t;
}
#endif

static __device__ __forceinline__ float partner32(float v, int hi) {
  unsigned u = __builtin_bit_cast(unsigned, v);
  unsigned lo_, hi_;
  pl32_swap(u, u, lo_, hi_);
  return __builtin_bit_cast(float, hi ? lo_ : hi_);
}

// ---------------- fp32 -> fp16 convert (x) ----------------
__global__ __launch_bounds__(256) void cvt_f32_f16(const float* __restrict__ in,
                                                   _Float16* __restrict__ out, int n) {
  int i = (blockIdx.x * 256 + threadIdx.x) * 4;
  if (i >= n) return;
  float4 v = *(const float4*)(in + i);
  half4v o;
  o[0] = (_Float16)v.x; o[1] = (_Float16)v.y; o[2] = (_Float16)v.z; o[3] = (_Float16)v.w;
  *(half4v*)(out + i) = o;
}

// ---------------- fp32 -> fp16 convert, 4 weight matrices in one launch ----------------
__global__ __launch_bounds__(256) void cvt_w4(const float* __restrict__ w0, const float* __restrict__ w1,
                                              const float* __restrict__ w2, const float* __restrict__ w3,
                                              _Float16* __restrict__ o0, _Float16* __restrict__ o1,
                                              _Float16* __restrict__ o2, _Float16* __restrict__ o3) {
  const int z = blockIdx.y;
  const float* in = (z == 0) ? w0 : (z == 1) ? w1 : (z == 2) ? w2 : w3;
  _Float16* out = (z == 0) ? o0 : (z == 1) ? o1 : (z == 2) ? o2 : o3;
  int i = (blockIdx.x * 256 + threadIdx.x) * 4;
  float4 v = *(const float4*)(in + i);
  half4v o;
  o[0] = (_Float16)v.x; o[1] = (_Float16)v.y; o[2] = (_Float16)v.z; o[3] = (_Float16)v.w;
  *(half4v*)(out + i) = o;
}

// ---------------- mask prep v3: format detect + deterministic compaction scan ----------------
// One block per batch b. Outputs: qmask (0/1 f32), ks[b][2048] compacted unmasked indices
// (pad = dup of last valid), maskc[b][j] = 0 (j<nk) else -60000, nk64a[b] = ceil64(nk).
__global__ __launch_bounds__(256) void mask_prep(const unsigned char* __restrict__ mraw,
                                                 _Float16* __restrict__ maskc,
                                                 float* __restrict__ qmask,
                                                 int* __restrict__ ks,
                                                 int* __restrict__ nk64a) {
  __shared__ int flags[2];
  __shared__ int psum[256];
  const int b = blockIdx.x, tid = threadIdx.x;
  if (tid < 2) flags[tid] = 1;
  __syncthreads();
  const unsigned int* w = (const unsigned int*)mraw;
  for (int i = tid; i < 2048; i += 256) {  // first 8KiB format scan
    unsigned int v = w[i];
    if (!(v == 0u || v == 1u)) flags[0] = 0;
    if (!(v == 0u || v == 0x3f800000u)) flags[1] = 0;
  }
  __syncthreads();
  const int is_i32 = flags[0], is_f32 = flags[1];
  int m[8]; int cnt = 0;
  for (int i = 0; i < 8; ++i) {
    const int idx = b * 2048 + tid * 8 + i;
    int mv;
    if (is_i32)      mv = ((const int*)mraw)[idx];
    else if (is_f32) mv = (((const unsigned int*)mraw)[idx] != 0u);
    else             mv = (mraw[idx] != 0);
    m[i] = mv; cnt += mv;
    qmask[idx] = mv ? 1.0f : 0.0f;
  }
  psum[tid] = cnt;
  __syncthreads();
  for (int off = 1; off < 256; off <<= 1) {
    int u = (tid >= off) ? psum[tid - off] : 0;
    __syncthreads();
    psum[tid] += u;
    __syncthreads();
  }
  const int total = psum[255];
  int base = psum[tid] - cnt;  // exclusive prefix
  for (int i = 0; i < 8; ++i)
    if (m[i]) ks[b * 2048 + (base++)] = tid * 8 + i;
  for (int j = tid; j < 2048; j += 256)
    maskc[b * 2048 + j] = (j < total) ? (_Float16)0.0f : (_Float16)(-60000.0f);
  __syncthreads();
  const int lastv = (total > 0) ? ks[b * 2048 + total - 1] : 0;
  for (int j = total + tid; j < 2048; j += 256)
    ks[b * 2048 + j] = lastv;
  if (tid == 0) nk64a[b] = (total + 63) & ~63;
}

// ---------------- GEMM staging: 128 rows x 32 f16 cols -> LDS (linear) ----------------
__device__ __forceinline__ void stage128x32(const _Float16* __restrict__ g, int ld,
                                            _Float16* lds, int wid, int lane) {
#pragma unroll
  for (int j = 0; j < 2; ++j) {
    const int c = j * 256 + wid * 64 + lane;
    const _Float16* src = g + (size_t)(c >> 2) * ld + (c & 3) * 8;
    _Float16* dst = lds + (size_t)(j * 256 + wid * 64) * 8;
    __builtin_amdgcn_global_load_lds((gconst_void*)src, (lds_void*)dst, 16, 0, 0);
  }
}

// ---------------- QKV projection GEMM ----------------
__global__ __launch_bounds__(256) void qkv_gemm(
    const _Float16* __restrict__ xh,
    const _Float16* __restrict__ wq, const _Float16* __restrict__ wk, const _Float16* __restrict__ wv,
    const float* __restrict__ bq, const float* __restrict__ bkp, const float* __restrict__ bvp,
    _Float16* __restrict__ Qh, _Float16* __restrict__ Kh, _Float16* __restrict__ Vth) {
  __shared__ _Float16 As[128 * 32];
  __shared__ _Float16 Bs[128 * 32];
  const int tid = threadIdx.x, lane = tid & 63, wid = tid >> 6;
  const int g = lane >> 4, r16 = lane & 15;
  const int bm = blockIdx.x * 128, bn = blockIdx.y * 128;
  const int z = blockIdx.z;
  const _Float16* w = (z == 0) ? wq : (z == 1) ? wk : wv;
  const float* bias = (z == 0) ? bq : (z == 1) ? bkp : bvp;
  const int wr = wid >> 1, wc = wid & 1;
  f32x4 acc[4][4] = {};
  for (int k0 = 0; k0 < E_; k0 += 32) {
    stage128x32(xh + (size_t)bm * E_ + k0, E_, As, wid, lane);
    stage128x32(w + (size_t)bn * E_ + k0, E_, Bs, wid, lane);
    __syncthreads();
    half8v a[4], bf[4];
#pragma unroll
    for (int i = 0; i < 4; ++i) a[i] = *(const half8v*)&As[(wr * 64 + i * 16 + r16) * 32 + g * 8];
#pragma unroll
    for (int i = 0; i < 4; ++i) bf[i] = *(const half8v*)&Bs[(wc * 64 + i * 16 + r16) * 32 + g * 8];
#pragma unroll
    for (int i = 0; i < 4; ++i)
#pragma unroll
      for (int j = 0; j < 4; ++j) acc[i][j] = MFMA16(a[i], bf[j], acc[i][j]);
    __syncthreads();
  }
#pragma unroll
  for (int i = 0; i < 4; ++i) {
#pragma unroll
    for (int j = 0; j < 4; ++j) {
      const int gn = bn + wc * 64 + j * 16 + r16;
      const float bb = bias[gn];
      const int h = gn >> 6, d = gn & 63;
      const int gm0 = bm + wr * 64 + i * 16 + g * 4;
      const int bb_ = gm0 >> 11, s0 = gm0 & (S_ - 1);
      const size_t bhbase = (size_t)(bb_ * H_ + h) * S_ * D_;
      if (z == 2) {
        half4v v4;
#pragma unroll
        for (int ii = 0; ii < 4; ++ii) v4[ii] = (_Float16)(acc[i][j][ii] + bb);
        *(half4v*)&Vth[bhbase + (size_t)(s0 >> 4) * (D_ * 16) + d * 16 + (s0 & 15)] = v4;
      } else if (z == 1) {
#pragma unroll
        for (int ii = 0; ii < 4; ++ii) {
          const int s = s0 + ii;
          Kh[bhbase + (size_t)(s >> 5) * 2048 + (d >> 4) * 512 + (s & 31) * 16 + (d & 15)] =
              (_Float16)(acc[i][j][ii] + bb);
        }
      } else {
#pragma unroll
        for (int ii = 0; ii < 4; ++ii)
          Qh[bhbase + (size_t)(s0 + ii) * D_ + d] = (_Float16)((acc[i][j][ii] + bb) * QSCALE);
      }
    }
  }
}

// ---------------- K/V compaction: gather unmasked rows into frag-linear Kc/Vc ----------------
// One wave per (bh, jtile). Pads (j >= nk) copy the last valid row; maskc kills them in attn.
__global__ __launch_bounds__(64) void kv_compact(const _Float16* __restrict__ Kf,
                                                 const _Float16* __restrict__ Vf,
                                                 const int* __restrict__ ks,
                                                 const int* __restrict__ nk64a,
                                                 _Float16* __restrict__ Kc,
                                                 _Float16* __restrict__ Vc) {
  const int bhid = blockIdx.x;       // 0..63  (b*H + h)
  const int jt = blockIdx.y;         // 0..63  (32-row tiles)
  const int b = bhid >> 4;
  if (jt * 32 >= nk64a[b]) return;
  const int lane = threadIdx.x, c = lane & 31, hi = lane >> 5;
  const int j = jt * 32 + c;
  const int s = ks[b * 2048 + j];
  const size_t base = (size_t)bhid * S_ * D_;
  // K row s -> row j: frag-linear [tile][dc][row][16]
  {
    const size_t src = base + (size_t)(s >> 5) * 2048 + (s & 31) * 16;
    const size_t dst = base + (size_t)jt * 2048 + c * 16;
#pragma unroll
    for (int q = 0; q < 2; ++q) {
      const int dc = 2 * hi + q;
      *(half8v*)&Kc[dst + dc * 512 + 0] = *(const half8v*)&Kf[src + dc * 512 + 0];
      *(half8v*)&Kc[dst + dc * 512 + 8] = *(const half8v*)&Kf[src + dc * 512 + 8];
    }
  }
  // V row s -> row j: frag-linear [tile16][d][16]
  {
    const size_t srcb = base + (size_t)(s >> 4) * 1024 + (s & 15);
    const size_t dstb = base + (size_t)(j >> 4) * 1024 + (j & 15);
#pragma unroll
    for (int d0 = 0; d0 < 32; ++d0) {
      const int d = d0 + 32 * hi;
      Vc[dstb + d * 16] = Vf[srcb + d * 16];
    }
  }
}

// ---------------- flash attention v12: mask-compacted q & k ----------------
// KVBLK=32, k-split x2, XCD-swizzled 1D grid, pipelined K/mask prefetch.
// Only compacted (unmasked) q rows and k columns are processed.
__global__ __launch_bounds__(512) void attn_kernel(
    const _Float16* __restrict__ Qh, const _Float16* __restrict__ Kc, const _Float16* __restrict__ Vc,
    const _Float16* __restrict__ maskc, const int* __restrict__ ks, const int* __restrict__ nk64a,
    _Float16* __restrict__ Oh) {
  __shared__ float mlds[4][64][36];  // merge buffer; first 4KB aliased as mask row during loop
  _Float16* smask = (_Float16*)&mlds[0][0][0];
  const int tid = threadIdx.x, lane = tid & 63, wid = tid >> 6;
  const int c = lane & 31, hi = lane >> 5;
  const int qg = wid & 3, kh = wid >> 2;
  const int id = blockIdx.x;
  const int slot = id & 7, rest = id >> 3;
  const int t = rest & 15, hbh = rest >> 4;
  const int hb = hbh * 8 + slot;
  const int b = hb >> 4, h = hb & 15;
  const int nk64 = nk64a[b];
  if (t * 128 >= nk64) return;  // block-uniform early exit (before any barrier)
  const size_t bh = (size_t)(b * H_ + h);
  const _Float16* Qb = Qh + bh * S_ * D_;
  const _Float16* Kb = Kc + bh * S_ * D_;
  const _Float16* Vb = Vc + bh * S_ * D_;

  // stage compacted mask row (2048 f16 = 4KB) into LDS
  *((half4v*)smask + tid) = *((const half4v*)(maskc + (size_t)b * S_) + tid);

  // compacted q row for this lane (clamped pads -> benign duplicate work)
  const int jq = t * 128 + qg * 32 + c;
  const int qs = ks[b * 2048 + jq];

  // Q B-frags (pre-scaled): col=q, kdim d = 16*kc + 8*hi + j
  half8v qb[4];
#pragma unroll
  for (int kc = 0; kc < 4; ++kc)
    qb[kc] = *(const half8v*)&Qb[(size_t)qs * D_ + 16 * kc + 8 * hi];

  half8v bone = {};
  if (hi == 0) bone[0] = (_Float16)1.0f;  // B[kdim=0][q]=1 for rank-1 mask MFMA
  const f32x16 fzero = {};

  f32x16 oacc[2] = {};  // out^T[d][q]
  float mrun = -1e30f, lrun = 0.f;  // lrun is PER-HALF partial until after the loop
  const int laneoff = c * 16 + 8 * hi;
  const int nkh = nk64 >> 1;
  const int kb0 = kh * nkh;

  __syncthreads();  // mask staged

  // prefetch iter-0 K frags + mask value
  half8v kaf[4];
  {
    const _Float16* ktb = Kb + (size_t)(kb0 >> 5) * 2048 + laneoff;
#pragma unroll
    for (int kc = 0; kc < 4; ++kc) kaf[kc] = *(const half8v*)&ktb[kc * 512];
  }
  _Float16 mv = smask[kb0 + c];

  for (int kb = kb0; kb < kb0 + nkh; kb += 32) {
    // ---- QK^T from register-resident fragments ----
    half8v amask = {};
    if (hi == 0) amask[0] = mv;
    __builtin_amdgcn_s_setprio(1);
    f32x16 sc = MFMA32(amask, bone, fzero);
    sc = MFMA32(kaf[0], qb[0], sc);
    sc = MFMA32(kaf[1], qb[1], sc);
    sc = MFMA32(kaf[2], qb[2], sc);
    sc = MFMA32(kaf[3], qb[3], sc);
    __builtin_amdgcn_s_setprio(0);
    // ---- prefetch next-iter K frags + mask; V frags for this iter ----
    const int kbn = (kb + 32 < kb0 + nkh) ? kb + 32 : kb0;
    {
      const _Float16* ktb = Kb + (size_t)(kbn >> 5) * 2048 + laneoff;
#pragma unroll
      for (int kc = 0; kc < 4; ++kc) kaf[kc] = *(const half8v*)&ktb[kc * 512];
    }
    mv = smask[kbn + c];
    const _Float16* v_base = Vb + (size_t)(kb >> 4) * (D_ * 16) + laneoff;
    half8v va00 = *(const half8v*)&v_base[0];
    half8v va01 = *(const half8v*)&v_base[512];
    half8v va10 = *(const half8v*)&v_base[1024];
    half8v va11 = *(const half8v*)&v_base[1024 + 512];
    // ---- row max ----
    float t0 = fmaxf(sc[0], sc[4]), t1 = fmaxf(sc[1], sc[5]);
    float t2 = fmaxf(sc[2], sc[6]), t3 = fmaxf(sc[3], sc[7]);
    t0 = fmaxf(fmaxf(sc[8], sc[12]), t0);
    t1 = fmaxf(fmaxf(sc[9], sc[13]), t1);
    t2 = fmaxf(fmaxf(sc[10], sc[14]), t2);
    t3 = fmaxf(fmaxf(sc[11], sc[15]), t3);
    float pmax = fmaxf(fmaxf(t0, t1), fmaxf(t2, t3));
    pmax = fmaxf(pmax, partner32(pmax, hi));
    // ---- defer-max rescale (T13, log2 units) ----
    if (__any(pmax > mrun + 11.0f)) {
      float mnew = fmaxf(mrun, pmax);
      float corr = __builtin_amdgcn_exp2f(mrun - mnew);
      mrun = mnew;
      lrun *= corr;
#pragma unroll
      for (int dt = 0; dt < 2; ++dt)
#pragma unroll
        for (int r = 0; r < 16; ++r) oacc[dt][r] *= corr;
    }
    // ---- FUSED: exp2 + pack + permlane + PV ----
    float ps0 = 0.f, ps1 = 0.f;
#pragma unroll
    for (int sl = 0; sl < 2; ++sl) {
      const int bs = 8 * sl;
      float p0 = __builtin_amdgcn_exp2f(sc[bs + 0] - mrun);
      float p1 = __builtin_amdgcn_exp2f(sc[bs + 1] - mrun);
      float p2 = __builtin_amdgcn_exp2f(sc[bs + 2] - mrun);
      float p3 = __builtin_amdgcn_exp2f(sc[bs + 3] - mrun);
      float p4 = __builtin_amdgcn_exp2f(sc[bs + 4] - mrun);
      float p5 = __builtin_amdgcn_exp2f(sc[bs + 5] - mrun);
      float p6 = __builtin_amdgcn_exp2f(sc[bs + 6] - mrun);
      float p7 = __builtin_amdgcn_exp2f(sc[bs + 7] - mrun);
      ps0 += (p0 + p1) + (p2 + p3);
      ps1 += (p4 + p5) + (p6 + p7);
      unsigned uA = cvt_pk_u32(p0, p1);
      unsigned uB = cvt_pk_u32(p2, p3);
      unsigned uC = cvt_pk_u32(p4, p5);
      unsigned uD = cvt_pk_u32(p6, p7);
      unsigned w0, w1, w2, w3;
      pl32_swap(uA, uC, w0, w2);
      pl32_swap(uB, uD, w1, w3);
      uint4v u4 = {w0, w1, w2, w3};
      half8v pb = __builtin_bit_cast(half8v, u4);
      __builtin_amdgcn_s_setprio(1);
      oacc[0] = MFMA32(sl ? va10 : va00, pb, oacc[0]);
      oacc[1] = MFMA32(sl ? va11 : va01, pb, oacc[1]);
      __builtin_amdgcn_s_setprio(0);
    }
    lrun += ps0 + ps1;
  }
  // ---- cross-half lrun reduction (once) ----
  lrun += partner32(lrun, hi);
  // ---- k-split merge ----
  __syncthreads();
  if (kh == 1) {
    float* p = &mlds[qg][lane][0];
#pragma unroll
    for (int dt = 0; dt < 2; ++dt)
#pragma unroll
      for (int rr = 0; rr < 4; ++rr) {
        float4 v4 = make_float4(oacc[dt][4 * rr], oacc[dt][4 * rr + 1],
                                oacc[dt][4 * rr + 2], oacc[dt][4 * rr + 3]);
        *(float4*)&p[dt * 16 + rr * 4] = v4;
      }
    p[32] = mrun;
    p[33] = lrun;
  }
  __syncthreads();
  if (kh == 0) {
    const float* p = &mlds[qg][lane][0];
    const float mB = p[32], lB = p[33];
    const float mS = fmaxf(mrun, mB);
    const float cA = __builtin_amdgcn_exp2f(mrun - mS);
    const float cB = __builtin_amdgcn_exp2f(mB - mS);
    const float inv = 1.0f / (lrun * cA + lB * cB);
    const float fA = cA * inv, fB = cB * inv;
    _Float16* orow = Oh + ((size_t)(b * S_ + qs)) * E_ + h * D_;
#pragma unroll
    for (int dt = 0; dt < 2; ++dt)
#pragma unroll
      for (int rr = 0; rr < 4; ++rr) {
        float4 vB = *(const float4*)&p[dt * 16 + rr * 4];
        half4v o4;
        o4[0] = (_Float16)(oacc[dt][4 * rr + 0] * fA + vB.x * fB);
        o4[1] = (_Float16)(oacc[dt][4 * rr + 1] * fA + vB.y * fB);
        o4[2] = (_Float16)(oacc[dt][4 * rr + 2] * fA + vB.z * fB);
        o4[3] = (_Float16)(oacc[dt][4 * rr + 3] * fA + vB.w * fB);
        *(half4v*)&orow[32 * dt + 8 * rr + 4 * hi] = o4;
      }
  }
}

// ---------------- output projection + abs(o*mask), fp32 out ----------------
__global__ __launch_bounds__(256) void oproj_gemm(
    const _Float16* __restrict__ Oh, const _Float16* __restrict__ wo, const float* __restrict__ bo,
    const float* __restrict__ qmask, float* __restrict__ out) {
  __shared__ _Float16 As[128 * 32];
  __shared__ _Float16 Bs[128 * 32];
  const int tid = threadIdx.x, lane = tid & 63, wid = tid >> 6;
  const int g = lane >> 4, r16 = lane & 15;
  const int bm = blockIdx.x * 128, bn = blockIdx.y * 128;
  const int wr = wid >> 1, wc = wid & 1;
  f32x4 acc[4][4] = {};
  for (int k0 = 0; k0 < E_; k0 += 32) {
    stage128x32(Oh + (size_t)bm * E_ + k0, E_, As, wid, lane);
    stage128x32(wo + (size_t)bn * E_ + k0, E_, Bs, wid, lane);
    __syncthreads();
    half8v a[4], bf[4];
#pragma unroll
    for (int i = 0; i < 4; ++i) a[i] = *(const half8v*)&As[(wr * 64 + i * 16 + r16) * 32 + g * 8];
#pragma unroll
    for (int i = 0; i < 4; ++i) bf[i] = *(const half8v*)&Bs[(wc * 64 + i * 16 + r16) * 32 + g * 8];
#pragma unroll
    for (int i = 0; i < 4; ++i)
#pragma unroll
      for (int j = 0; j < 4; ++j) acc[i][j] = MFMA16(a[i], bf[j], acc[i][j]);
    __syncthreads();
  }
#pragma unroll
  for (int i = 0; i < 4; ++i) {
#pragma unroll
    for (int j = 0; j < 4; ++j) {
      const int gn = bn + wc * 64 + j * 16 + r16;
      const float bb = bo[gn];
      const int gm0 = bm + wr * 64 + i * 16 + g * 4;
#pragma unroll
      for (int ii = 0; ii < 4; ++ii) {
        const int gm = gm0 + ii;
        const float y = acc[i][j][ii] + bb;
        out[(size_t)gm * E_ + gn] = fabsf(y * qmask[gm]);
      }
    }
  }
}

extern "C" void kernel_launch(void* const* d_in, const int* in_sizes, int n_in,
                              void* d_out, int out_size, void* d_ws, size_t ws_size,
                              hipStream_t stream) {
  const float* x = (const float*)d_in[0];
  const unsigned char* mask = (const unsigned char*)d_in[1];
  const float* WQ_w = (const float*)d_in[2];
  const float* WQ_b = (const float*)d_in[3];
  const float* WK_w = (const float*)d_in[4];
  const float* WK_b = (const float*)d_in[5];
  const float* WV_w = (const float*)d_in[6];
  const float* WV_b = (const float*)d_in[7];
  const float* WO_w = (const float*)d_in[8];
  const float* WO_b = (const float*)d_in[9];

  char* ws = (char*)d_ws;
  size_t off = 0;
  _Float16* xh  = (_Float16*)(ws + off); off += (size_t)MTOT * E_ * 2;  // reused as O after attn
  _Float16* wqh = (_Float16*)(ws + off); off += (size_t)E_ * E_ * 2;
  _Float16* wkh = (_Float16*)(ws + off); off += (size_t)E_ * E_ * 2;
  _Float16* wvh = (_Float16*)(ws + off); off += (size_t)E_ * E_ * 2;
  _Float16* woh = (_Float16*)(ws + off); off += (size_t)E_ * E_ * 2;
  _Float16* Qh  = (_Float16*)(ws + off); off += (size_t)MTOT * E_ * 2;
  _Float16* Kh  = (_Float16*)(ws + off); off += (size_t)MTOT * E_ * 2;
  _Float16* Vth = (_Float16*)(ws + off); off += (size_t)MTOT * E_ * 2;
  _Float16* Kc  = (_Float16*)(ws + off); off += (size_t)MTOT * E_ * 2;
  _Float16* Vc  = (_Float16*)(ws + off); off += (size_t)MTOT * E_ * 2;
  _Float16* maskcf = (_Float16*)(ws + off); off += (size_t)B_ * S_ * 2;
  float* qmaskf = (float*)(ws + off); off += (size_t)B_ * S_ * 4;
  int* ksl      = (int*)(ws + off); off += (size_t)B_ * S_ * 4;
  int* nk64a    = (int*)(ws + off); off += 64;
  if (ws_size < off) return;

  const int NX = MTOT * E_;   // 8388608
  const int NW = E_ * E_;     // 1048576
  cvt_f32_f16<<<dim3(NX / 4 / 256), dim3(256), 0, stream>>>(x, xh, NX);
  cvt_w4<<<dim3(NW / 4 / 256, 4), dim3(256), 0, stream>>>(WQ_w, WK_w, WV_w, WO_w,
                                                          wqh, wkh, wvh, woh);
  mask_prep<<<dim3(B_), dim3(256), 0, stream>>>(mask, maskcf, qmaskf, ksl, nk64a);
  qkv_gemm<<<dim3(MTOT / 128, E_ / 128, 3), dim3(256), 0, stream>>>(
      xh, wqh, wkh, wvh, WQ_b, WK_b, WV_b, Qh, Kh, Vth);
  kv_compact<<<dim3(B_ * H_, S_ / 32), dim3(64), 0, stream>>>(Kh, Vth, ksl, nk64a, Kc, Vc);
  attn_kernel<<<dim3((S_ / 128) * H_ * B_), dim3(512), 0, stream>>>(
      Qh, Kc, Vc, maskcf, ksl, nk64a, xh);
  oproj_gemm<<<dim3(MTOT / 128, E_ / 128), dim3(256), 0, stream>>>(xh, woh, WO_b, qmaskf, (float*)d_out);
}

// Round 16
// 152.222 us; speedup vs baseline: 1.7107x; 1.1174x over previous
//
#include <hip/hip_runtime.h>
#include <math.h>

#define B_ 4
#define S_ 2048
#define E_ 1024
#define H_ 16
#define D_ 64
#define MTOT (B_*S_)

typedef _Float16 half8v __attribute__((ext_vector_type(8)));
typedef _Float16 half4v __attribute__((ext_vector_type(4)));
typedef float f32x4 __attribute__((ext_vector_type(4)));
typedef float f32x16 __attribute__((ext_vector_type(16)));
typedef unsigned uint4v __attribute__((ext_vector_type(4)));

typedef __attribute__((address_space(1))) const void gconst_void;
typedef __attribute__((address_space(3))) void lds_void;

#define MFMA16(a,b,c) __builtin_amdgcn_mfma_f32_16x16x32_f16((a),(b),(c),0,0,0)
#define MFMA32(a,b,c) __builtin_amdgcn_mfma_f32_32x32x16_f16((a),(b),(c),0,0,0)

#define QSCALE 0.18033688011112042f  /* 0.125 * log2(e): folded into Q at projection */

static __device__ __forceinline__ unsigned cvt_pk_u32(float a, float b) {
  return __builtin_bit_cast(unsigned, __builtin_amdgcn_cvt_pkrtz(a, b));
}

#if __has_builtin(__builtin_amdgcn_permlane32_swap)
static __device__ __forceinline__ void pl32_swap(unsigned a, unsigned b,
                                                 unsigned& rlo, unsigned& rhi) {
  auto r = __builtin_amdgcn_permlane32_swap(a, b, false, false);
  rlo = r[0]; rhi = r[1];
}
#else
static __device__ __forceinline__ void pl32_swap(unsigned a, unsigned b,
                                                 unsigned& rlo, unsigned& rhi) {
  const int hi = (threadIdx.x & 63) >> 5;
  unsigned t = __shfl_xor(hi ? a : b, 32);
  rlo = hi ? t : a;
  rhi = hi ? b : t;
}
#endif

static __device__ __forceinline__ float partner32(float v, int hi) {
  unsigned u = __builtin_bit_cast(unsigned, v);
  unsigned lo_, hi_;
  pl32_swap(u, u, lo_, hi_);
  return __builtin_bit_cast(float, hi ? lo_ : hi_);
}

// ---------------- fp32 -> fp16 convert, 4 weight matrices in one launch ----------------
__global__ __launch_bounds__(256) void cvt_w4(const float* __restrict__ w0, const float* __restrict__ w1,
                                              const float* __restrict__ w2, const float* __restrict__ w3,
                                              _Float16* __restrict__ o0, _Float16* __restrict__ o1,
                                              _Float16* __restrict__ o2, _Float16* __restrict__ o3) {
  const int z = blockIdx.y;
  const float* in = (z == 0) ? w0 : (z == 1) ? w1 : (z == 2) ? w2 : w3;
  _Float16* out = (z == 0) ? o0 : (z == 1) ? o1 : (z == 2) ? o2 : o3;
  int i = (blockIdx.x * 256 + threadIdx.x) * 4;
  float4 v = *(const float4*)(in + i);
  half4v o;
  o[0] = (_Float16)v.x; o[1] = (_Float16)v.y; o[2] = (_Float16)v.z; o[3] = (_Float16)v.w;
  *(half4v*)(out + i) = o;
}

// ---------------- mask prep v4: format detect + compaction scan (pad to 128) ----------------
// One block per batch b. Outputs: qmask (0/1 f32), ks[b][2048] compacted unmasked indices
// (pads dup last valid), maskc[b][j] = 0 (j<nk) else -60000, nkpa[b] = ceil128(nk).
__global__ __launch_bounds__(256) void mask_prep(const unsigned char* __restrict__ mraw,
                                                 _Float16* __restrict__ maskc,
                                                 float* __restrict__ qmask,
                                                 int* __restrict__ ks,
                                                 int* __restrict__ nkpa) {
  __shared__ int flags[2];
  __shared__ int psum[256];
  const int b = blockIdx.x, tid = threadIdx.x;
  if (tid < 2) flags[tid] = 1;
  __syncthreads();
  const unsigned int* w = (const unsigned int*)mraw;
  for (int i = tid; i < 2048; i += 256) {  // first 8KiB format scan
    unsigned int v = w[i];
    if (!(v == 0u || v == 1u)) flags[0] = 0;
    if (!(v == 0u || v == 0x3f800000u)) flags[1] = 0;
  }
  __syncthreads();
  const int is_i32 = flags[0], is_f32 = flags[1];
  int m[8]; int cnt = 0;
  for (int i = 0; i < 8; ++i) {
    const int idx = b * 2048 + tid * 8 + i;
    int mv;
    if (is_i32)      mv = ((const int*)mraw)[idx];
    else if (is_f32) mv = (((const unsigned int*)mraw)[idx] != 0u);
    else             mv = (mraw[idx] != 0);
    m[i] = mv; cnt += mv;
    qmask[idx] = mv ? 1.0f : 0.0f;
  }
  psum[tid] = cnt;
  __syncthreads();
  for (int off = 1; off < 256; off <<= 1) {
    int u = (tid >= off) ? psum[tid - off] : 0;
    __syncthreads();
    psum[tid] += u;
    __syncthreads();
  }
  const int total = psum[255];
  int base = psum[tid] - cnt;  // exclusive prefix
  for (int i = 0; i < 8; ++i)
    if (m[i]) ks[b * 2048 + (base++)] = tid * 8 + i;
  for (int j = tid; j < 2048; j += 256)
    maskc[b * 2048 + j] = (j < total) ? (_Float16)0.0f : (_Float16)(-60000.0f);
  __syncthreads();
  const int lastv = (total > 0) ? ks[b * 2048 + total - 1] : 0;
  for (int j = total + tid; j < 2048; j += 256)
    ks[b * 2048 + j] = lastv;
  if (tid == 0) nkpa[b] = (total + 127) & ~127;
}

// ---------------- gather-convert x rows into compacted xc (f16) ----------------
// One block per (compacted row j, batch b); pads (j in [nk, nkp)) duplicate last valid row.
__global__ __launch_bounds__(256) void cvt_xc(const float* __restrict__ x,
                                              const int* __restrict__ ks,
                                              const int* __restrict__ nkpa,
                                              _Float16* __restrict__ xc) {
  const int b = blockIdx.y, j = blockIdx.x;
  if (j >= nkpa[b]) return;
  const int s = ks[b * 2048 + j];
  const float* src = x + (size_t)(b * 2048 + s) * E_;
  _Float16* dst = xc + (size_t)(b * 2048 + j) * E_;
  const int i = threadIdx.x * 4;
  float4 v = *(const float4*)(src + i);
  half4v o;
  o[0] = (_Float16)v.x; o[1] = (_Float16)v.y; o[2] = (_Float16)v.z; o[3] = (_Float16)v.w;
  *(half4v*)(dst + i) = o;
}

// ---------------- GEMM staging: 128 rows x 32 f16 cols -> LDS (linear) ----------------
__device__ __forceinline__ void stage128x32(const _Float16* __restrict__ g, int ld,
                                            _Float16* lds, int wid, int lane) {
#pragma unroll
  for (int j = 0; j < 2; ++j) {
    const int c = j * 256 + wid * 64 + lane;
    const _Float16* src = g + (size_t)(c >> 2) * ld + (c & 3) * 8;
    _Float16* dst = lds + (size_t)(j * 256 + wid * 64) * 8;
    __builtin_amdgcn_global_load_lds((gconst_void*)src, (lds_void*)dst, 16, 0, 0);
  }
}

// ---------------- QKV projection GEMM on COMPACTED rows ----------------
// A = xc (compacted per batch, 16 tiles/batch, early-exit past nkp).
// Qc row-major compacted (B,H,j,D) pre-scaled; Kc frag-linear [bh][j>>5][dc][j&31][16];
// Vc frag-linear [bh][j>>4][d][j&15].
__global__ __launch_bounds__(256) void qkv_gemm(
    const _Float16* __restrict__ xc, const int* __restrict__ nkpa,
    const _Float16* __restrict__ wq, const _Float16* __restrict__ wk, const _Float16* __restrict__ wv,
    const float* __restrict__ bq, const float* __restrict__ bkp, const float* __restrict__ bvp,
    _Float16* __restrict__ Qc, _Float16* __restrict__ Kc, _Float16* __restrict__ Vc) {
  const int bx = blockIdx.x;
  const int bb = bx >> 4, tt = bx & 15;
  if (tt * 128 >= nkpa[bb]) return;  // block-uniform exit before any barrier
  __shared__ _Float16 As[128 * 32];
  __shared__ _Float16 Bs[128 * 32];
  const int tid = threadIdx.x, lane = tid & 63, wid = tid >> 6;
  const int g = lane >> 4, r16 = lane & 15;
  const int bm = bx * 128, bn = blockIdx.y * 128;
  const int z = blockIdx.z;
  const _Float16* w = (z == 0) ? wq : (z == 1) ? wk : wv;
  const float* bias = (z == 0) ? bq : (z == 1) ? bkp : bvp;
  const int wr = wid >> 1, wc = wid & 1;
  f32x4 acc[4][4] = {};
  for (int k0 = 0; k0 < E_; k0 += 32) {
    stage128x32(xc + (size_t)bm * E_ + k0, E_, As, wid, lane);
    stage128x32(w + (size_t)bn * E_ + k0, E_, Bs, wid, lane);
    __syncthreads();
    half8v a[4], bf[4];
#pragma unroll
    for (int i = 0; i < 4; ++i) a[i] = *(const half8v*)&As[(wr * 64 + i * 16 + r16) * 32 + g * 8];
#pragma unroll
    for (int i = 0; i < 4; ++i) bf[i] = *(const half8v*)&Bs[(wc * 64 + i * 16 + r16) * 32 + g * 8];
#pragma unroll
    for (int i = 0; i < 4; ++i)
#pragma unroll
      for (int j = 0; j < 4; ++j) acc[i][j] = MFMA16(a[i], bf[j], acc[i][j]);
    __syncthreads();
  }
#pragma unroll
  for (int i = 0; i < 4; ++i) {
#pragma unroll
    for (int j = 0; j < 4; ++j) {
      const int gn = bn + wc * 64 + j * 16 + r16;
      const float bb2 = bias[gn];
      const int h = gn >> 6, d = gn & 63;
      const int gm0 = bm + wr * 64 + i * 16 + g * 4;
      const int b_ = gm0 >> 11, s0 = gm0 & (S_ - 1);
      const size_t bhbase = (size_t)(b_ * H_ + h) * S_ * D_;
      if (z == 2) {
        half4v v4;
#pragma unroll
        for (int ii = 0; ii < 4; ++ii) v4[ii] = (_Float16)(acc[i][j][ii] + bb2);
        *(half4v*)&Vc[bhbase + (size_t)(s0 >> 4) * (D_ * 16) + d * 16 + (s0 & 15)] = v4;
      } else if (z == 1) {
#pragma unroll
        for (int ii = 0; ii < 4; ++ii) {
          const int s = s0 + ii;
          Kc[bhbase + (size_t)(s >> 5) * 2048 + (d >> 4) * 512 + (s & 31) * 16 + (d & 15)] =
              (_Float16)(acc[i][j][ii] + bb2);
        }
      } else {
#pragma unroll
        for (int ii = 0; ii < 4; ++ii)
          Qc[bhbase + (size_t)(s0 + ii) * D_ + d] = (_Float16)((acc[i][j][ii] + bb2) * QSCALE);
      }
    }
  }
}

// ---------------- flash attention v13: fully compacted q & k ----------------
// KVBLK=32, k-split x2, XCD-swizzled 1D grid, pipelined K/mask prefetch.
// Q read at compacted index; O scattered to original row via ks.
__global__ __launch_bounds__(512) void attn_kernel(
    const _Float16* __restrict__ Qc, const _Float16* __restrict__ Kc, const _Float16* __restrict__ Vc,
    const _Float16* __restrict__ maskc, const int* __restrict__ ks, const int* __restrict__ nkpa,
    _Float16* __restrict__ Oh) {
  __shared__ float mlds[4][64][36];  // merge buffer; first 4KB aliased as mask row during loop
  _Float16* smask = (_Float16*)&mlds[0][0][0];
  const int tid = threadIdx.x, lane = tid & 63, wid = tid >> 6;
  const int c = lane & 31, hi = lane >> 5;
  const int qg = wid & 3, kh = wid >> 2;
  const int id = blockIdx.x;
  const int slot = id & 7, rest = id >> 3;
  const int t = rest & 15, hbh = rest >> 4;
  const int hb = hbh * 8 + slot;
  const int b = hb >> 4, h = hb & 15;
  const int nkp = nkpa[b];
  if (t * 128 >= nkp) return;  // block-uniform early exit (before any barrier)
  const size_t bh = (size_t)(b * H_ + h);
  const _Float16* Qb = Qc + bh * S_ * D_;
  const _Float16* Kb = Kc + bh * S_ * D_;
  const _Float16* Vb = Vc + bh * S_ * D_;

  // stage compacted mask row (2048 f16 = 4KB) into LDS
  *((half4v*)smask + tid) = *((const half4v*)(maskc + (size_t)b * S_) + tid);

  const int jq = t * 128 + qg * 32 + c;      // compacted q row
  const int qs = ks[b * 2048 + jq];          // original row (for O scatter)

  // Q B-frags (pre-scaled): col=q, kdim d = 16*kc + 8*hi + j
  half8v qb[4];
#pragma unroll
  for (int kc = 0; kc < 4; ++kc)
    qb[kc] = *(const half8v*)&Qb[(size_t)jq * D_ + 16 * kc + 8 * hi];

  half8v bone = {};
  if (hi == 0) bone[0] = (_Float16)1.0f;  // B[kdim=0][q]=1 for rank-1 mask MFMA
  const f32x16 fzero = {};

  f32x16 oacc[2] = {};  // out^T[d][q]
  float mrun = -1e30f, lrun = 0.f;  // lrun is PER-HALF partial until after the loop
  const int laneoff = c * 16 + 8 * hi;
  const int nkh = nkp >> 1;
  const int kb0 = kh * nkh;

  __syncthreads();  // mask staged

  // prefetch iter-0 K frags + mask value
  half8v kaf[4];
  {
    const _Float16* ktb = Kb + (size_t)(kb0 >> 5) * 2048 + laneoff;
#pragma unroll
    for (int kc = 0; kc < 4; ++kc) kaf[kc] = *(const half8v*)&ktb[kc * 512];
  }
  _Float16 mv = smask[kb0 + c];

  for (int kb = kb0; kb < kb0 + nkh; kb += 32) {
    // ---- QK^T from register-resident fragments ----
    half8v amask = {};
    if (hi == 0) amask[0] = mv;
    __builtin_amdgcn_s_setprio(1);
    f32x16 sc = MFMA32(amask, bone, fzero);
    sc = MFMA32(kaf[0], qb[0], sc);
    sc = MFMA32(kaf[1], qb[1], sc);
    sc = MFMA32(kaf[2], qb[2], sc);
    sc = MFMA32(kaf[3], qb[3], sc);
    __builtin_amdgcn_s_setprio(0);
    // ---- prefetch next-iter K frags + mask; V frags for this iter ----
    const int kbn = (kb + 32 < kb0 + nkh) ? kb + 32 : kb0;
    {
      const _Float16* ktb = Kb + (size_t)(kbn >> 5) * 2048 + laneoff;
#pragma unroll
      for (int kc = 0; kc < 4; ++kc) kaf[kc] = *(const half8v*)&ktb[kc * 512];
    }
    mv = smask[kbn + c];
    const _Float16* v_base = Vb + (size_t)(kb >> 4) * (D_ * 16) + laneoff;
    half8v va00 = *(const half8v*)&v_base[0];
    half8v va01 = *(const half8v*)&v_base[512];
    half8v va10 = *(const half8v*)&v_base[1024];
    half8v va11 = *(const half8v*)&v_base[1024 + 512];
    // ---- row max ----
    float t0 = fmaxf(sc[0], sc[4]), t1 = fmaxf(sc[1], sc[5]);
    float t2 = fmaxf(sc[2], sc[6]), t3 = fmaxf(sc[3], sc[7]);
    t0 = fmaxf(fmaxf(sc[8], sc[12]), t0);
    t1 = fmaxf(fmaxf(sc[9], sc[13]), t1);
    t2 = fmaxf(fmaxf(sc[10], sc[14]), t2);
    t3 = fmaxf(fmaxf(sc[11], sc[15]), t3);
    float pmax = fmaxf(fmaxf(t0, t1), fmaxf(t2, t3));
    pmax = fmaxf(pmax, partner32(pmax, hi));
    // ---- defer-max rescale (T13, log2 units) ----
    if (__any(pmax > mrun + 11.0f)) {
      float mnew = fmaxf(mrun, pmax);
      float corr = __builtin_amdgcn_exp2f(mrun - mnew);
      mrun = mnew;
      lrun *= corr;
#pragma unroll
      for (int dt = 0; dt < 2; ++dt)
#pragma unroll
        for (int r = 0; r < 16; ++r) oacc[dt][r] *= corr;
    }
    // ---- FUSED: exp2 + pack + permlane + PV ----
    float ps0 = 0.f, ps1 = 0.f;
#pragma unroll
    for (int sl = 0; sl < 2; ++sl) {
      const int bs = 8 * sl;
      float p0 = __builtin_amdgcn_exp2f(sc[bs + 0] - mrun);
      float p1 = __builtin_amdgcn_exp2f(sc[bs + 1] - mrun);
      float p2 = __builtin_amdgcn_exp2f(sc[bs + 2] - mrun);
      float p3 = __builtin_amdgcn_exp2f(sc[bs + 3] - mrun);
      float p4 = __builtin_amdgcn_exp2f(sc[bs + 4] - mrun);
      float p5 = __builtin_amdgcn_exp2f(sc[bs + 5] - mrun);
      float p6 = __builtin_amdgcn_exp2f(sc[bs + 6] - mrun);
      float p7 = __builtin_amdgcn_exp2f(sc[bs + 7] - mrun);
      ps0 += (p0 + p1) + (p2 + p3);
      ps1 += (p4 + p5) + (p6 + p7);
      unsigned uA = cvt_pk_u32(p0, p1);
      unsigned uB = cvt_pk_u32(p2, p3);
      unsigned uC = cvt_pk_u32(p4, p5);
      unsigned uD = cvt_pk_u32(p6, p7);
      unsigned w0, w1, w2, w3;
      pl32_swap(uA, uC, w0, w2);
      pl32_swap(uB, uD, w1, w3);
      uint4v u4 = {w0, w1, w2, w3};
      half8v pb = __builtin_bit_cast(half8v, u4);
      __builtin_amdgcn_s_setprio(1);
      oacc[0] = MFMA32(sl ? va10 : va00, pb, oacc[0]);
      oacc[1] = MFMA32(sl ? va11 : va01, pb, oacc[1]);
      __builtin_amdgcn_s_setprio(0);
    }
    lrun += ps0 + ps1;
  }
  // ---- cross-half lrun reduction (once) ----
  lrun += partner32(lrun, hi);
  // ---- k-split merge ----
  __syncthreads();
  if (kh == 1) {
    float* p = &mlds[qg][lane][0];
#pragma unroll
    for (int dt = 0; dt < 2; ++dt)
#pragma unroll
      for (int rr = 0; rr < 4; ++rr) {
        float4 v4 = make_float4(oacc[dt][4 * rr], oacc[dt][4 * rr + 1],
                                oacc[dt][4 * rr + 2], oacc[dt][4 * rr + 3]);
        *(float4*)&p[dt * 16 + rr * 4] = v4;
      }
    p[32] = mrun;
    p[33] = lrun;
  }
  __syncthreads();
  if (kh == 0) {
    const float* p = &mlds[qg][lane][0];
    const float mB = p[32], lB = p[33];
    const float mS = fmaxf(mrun, mB);
    const float cA = __builtin_amdgcn_exp2f(mrun - mS);
    const float cB = __builtin_amdgcn_exp2f(mB - mS);
    const float inv = 1.0f / (lrun * cA + lB * cB);
    const float fA = cA * inv, fB = cB * inv;
    _Float16* orow = Oh + ((size_t)(b * S_ + qs)) * E_ + h * D_;
#pragma unroll
    for (int dt = 0; dt < 2; ++dt)
#pragma unroll
      for (int rr = 0; rr < 4; ++rr) {
        float4 vB = *(const float4*)&p[dt * 16 + rr * 4];
        half4v o4;
        o4[0] = (_Float16)(oacc[dt][4 * rr + 0] * fA + vB.x * fB);
        o4[1] = (_Float16)(oacc[dt][4 * rr + 1] * fA + vB.y * fB);
        o4[2] = (_Float16)(oacc[dt][4 * rr + 2] * fA + vB.z * fB);
        o4[3] = (_Float16)(oacc[dt][4 * rr + 3] * fA + vB.w * fB);
        *(half4v*)&orow[32 * dt + 8 * rr + 4 * hi] = o4;
      }
  }
}

// ---------------- output projection + abs(o*mask), fp32 out ----------------
__global__ __launch_bounds__(256) void oproj_gemm(
    const _Float16* __restrict__ Oh, const _Float16* __restrict__ wo, const float* __restrict__ bo,
    const float* __restrict__ qmask, float* __restrict__ out) {
  __shared__ _Float16 As[128 * 32];
  __shared__ _Float16 Bs[128 * 32];
  const int tid = threadIdx.x, lane = tid & 63, wid = tid >> 6;
  const int g = lane >> 4, r16 = lane & 15;
  const int bm = blockIdx.x * 128, bn = blockIdx.y * 128;
  const int wr = wid >> 1, wc = wid & 1;
  f32x4 acc[4][4] = {};
  for (int k0 = 0; k0 < E_; k0 += 32) {
    stage128x32(Oh + (size_t)bm * E_ + k0, E_, As, wid, lane);
    stage128x32(wo + (size_t)bn * E_ + k0, E_, Bs, wid, lane);
    __syncthreads();
    half8v a[4], bf[4];
#pragma unroll
    for (int i = 0; i < 4; ++i) a[i] = *(const half8v*)&As[(wr * 64 + i * 16 + r16) * 32 + g * 8];
#pragma unroll
    for (int i = 0; i < 4; ++i) bf[i] = *(const half8v*)&Bs[(wc * 64 + i * 16 + r16) * 32 + g * 8];
#pragma unroll
    for (int i = 0; i < 4; ++i)
#pragma unroll
      for (int j = 0; j < 4; ++j) acc[i][j] = MFMA16(a[i], bf[j], acc[i][j]);
    __syncthreads();
  }
#pragma unroll
  for (int i = 0; i < 4; ++i) {
#pragma unroll
    for (int j = 0; j < 4; ++j) {
      const int gn = bn + wc * 64 + j * 16 + r16;
      const float bb = bo[gn];
      const int gm0 = bm + wr * 64 + i * 16 + g * 4;
#pragma unroll
      for (int ii = 0; ii < 4; ++ii) {
        const int gm = gm0 + ii;
        const float y = acc[i][j][ii] + bb;
        out[(size_t)gm * E_ + gn] = fabsf(y * qmask[gm]);
      }
    }
  }
}

extern "C" void kernel_launch(void* const* d_in, const int* in_sizes, int n_in,
                              void* d_out, int out_size, void* d_ws, size_t ws_size,
                              hipStream_t stream) {
  const float* x = (const float*)d_in[0];
  const unsigned char* mask = (const unsigned char*)d_in[1];
  const float* WQ_w = (const float*)d_in[2];
  const float* WQ_b = (const float*)d_in[3];
  const float* WK_w = (const float*)d_in[4];
  const float* WK_b = (const float*)d_in[5];
  const float* WV_w = (const float*)d_in[6];
  const float* WV_b = (const float*)d_in[7];
  const float* WO_w = (const float*)d_in[8];
  const float* WO_b = (const float*)d_in[9];

  char* ws = (char*)d_ws;
  size_t off = 0;
  _Float16* xc  = (_Float16*)(ws + off); off += (size_t)MTOT * E_ * 2;  // compacted x (f16)
  _Float16* wqh = (_Float16*)(ws + off); off += (size_t)E_ * E_ * 2;
  _Float16* wkh = (_Float16*)(ws + off); off += (size_t)E_ * E_ * 2;
  _Float16* wvh = (_Float16*)(ws + off); off += (size_t)E_ * E_ * 2;
  _Float16* woh = (_Float16*)(ws + off); off += (size_t)E_ * E_ * 2;
  _Float16* Qc  = (_Float16*)(ws + off); off += (size_t)MTOT * E_ * 2;
  _Float16* Kc  = (_Float16*)(ws + off); off += (size_t)MTOT * E_ * 2;
  _Float16* Vc  = (_Float16*)(ws + off); off += (size_t)MTOT * E_ * 2;
  _Float16* Obuf = (_Float16*)(ws + off); off += (size_t)MTOT * E_ * 2;
  _Float16* maskcf = (_Float16*)(ws + off); off += (size_t)B_ * S_ * 2;
  float* qmaskf = (float*)(ws + off); off += (size_t)B_ * S_ * 4;
  int* ksl      = (int*)(ws + off); off += (size_t)B_ * S_ * 4;
  int* nkpa     = (int*)(ws + off); off += 64;
  if (ws_size < off) return;

  const int NW = E_ * E_;     // 1048576
  mask_prep<<<dim3(B_), dim3(256), 0, stream>>>(mask, maskcf, qmaskf, ksl, nkpa);
  cvt_w4<<<dim3(NW / 4 / 256, 4), dim3(256), 0, stream>>>(WQ_w, WK_w, WV_w, WO_w,
                                                          wqh, wkh, wvh, woh);
  cvt_xc<<<dim3(S_, B_), dim3(256), 0, stream>>>(x, ksl, nkpa, xc);
  qkv_gemm<<<dim3(MTOT / 128, E_ / 128, 3), dim3(256), 0, stream>>>(
      xc, nkpa, wqh, wkh, wvh, WQ_b, WK_b, WV_b, Qc, Kc, Vc);
  attn_kernel<<<dim3((S_ / 128) * H_ * B_), dim3(512), 0, stream>>>(
      Qc, Kc, Vc, maskcf, ksl, nkpa, Obuf);
  oproj_gemm<<<dim3(MTOT / 128, E_ / 128), dim3(256), 0, stream>>>(Obuf, woh, WO_b, qmaskf, (float*)d_out);
}

// Round 17
// 150.581 us; speedup vs baseline: 1.7293x; 1.0109x over previous
//
#include <hip/hip_runtime.h>
#include <math.h>

#define B_ 4
#define S_ 2048
#define E_ 1024
#define H_ 16
#define D_ 64
#define MTOT (B_*S_)

typedef _Float16 half8v __attribute__((ext_vector_type(8)));
typedef _Float16 half4v __attribute__((ext_vector_type(4)));
typedef float f32x4 __attribute__((ext_vector_type(4)));
typedef float f32x16 __attribute__((ext_vector_type(16)));
typedef unsigned uint4v __attribute__((ext_vector_type(4)));

typedef __attribute__((address_space(1))) const void gconst_void;
typedef __attribute__((address_space(3))) void lds_void;

#define MFMA16(a,b,c) __builtin_amdgcn_mfma_f32_16x16x32_f16((a),(b),(c),0,0,0)
#define MFMA32(a,b,c) __builtin_amdgcn_mfma_f32_32x32x16_f16((a),(b),(c),0,0,0)

#define QSCALE 0.18033688011112042f  /* 0.125 * log2(e): folded into Q at projection */

static __device__ __forceinline__ unsigned cvt_pk_u32(float a, float b) {
  return __builtin_bit_cast(unsigned, __builtin_amdgcn_cvt_pkrtz(a, b));
}

#if __has_builtin(__builtin_amdgcn_permlane32_swap)
static __device__ __forceinline__ void pl32_swap(unsigned a, unsigned b,
                                                 unsigned& rlo, unsigned& rhi) {
  auto r = __builtin_amdgcn_permlane32_swap(a, b, false, false);
  rlo = r[0]; rhi = r[1];
}
#else
static __device__ __forceinline__ void pl32_swap(unsigned a, unsigned b,
                                                 unsigned& rlo, unsigned& rhi) {
  const int hi = (threadIdx.x & 63) >> 5;
  unsigned t = __shfl_xor(hi ? a : b, 32);
  rlo = hi ? t : a;
  rhi = hi ? b : t;
}
#endif

static __device__ __forceinline__ float partner32(float v, int hi) {
  unsigned u = __builtin_bit_cast(unsigned, v);
  unsigned lo_, hi_;
  pl32_swap(u, u, lo_, hi_);
  return __builtin_bit_cast(float, hi ? lo_ : hi_);
}

// ---------------- fp32 -> fp16 convert, 4 weight matrices in one launch ----------------
__global__ __launch_bounds__(256) void cvt_w4(const float* __restrict__ w0, const float* __restrict__ w1,
                                              const float* __restrict__ w2, const float* __restrict__ w3,
                                              _Float16* __restrict__ o0, _Float16* __restrict__ o1,
                                              _Float16* __restrict__ o2, _Float16* __restrict__ o3) {
  const int z = blockIdx.y;
  const float* in = (z == 0) ? w0 : (z == 1) ? w1 : (z == 2) ? w2 : w3;
  _Float16* out = (z == 0) ? o0 : (z == 1) ? o1 : (z == 2) ? o2 : o3;
  int i = (blockIdx.x * 256 + threadIdx.x) * 4;
  float4 v = *(const float4*)(in + i);
  half4v o;
  o[0] = (_Float16)v.x; o[1] = (_Float16)v.y; o[2] = (_Float16)v.z; o[3] = (_Float16)v.w;
  *(half4v*)(out + i) = o;
}

// ---------------- zero-fill fp32 output ----------------
__global__ __launch_bounds__(256) void zero_out(float* __restrict__ out) {
  const size_t i = ((size_t)blockIdx.x * 256 + threadIdx.x) * 4;
  float4 z = make_float4(0.f, 0.f, 0.f, 0.f);
  *(float4*)(out + i) = z;
}

// ---------------- mask prep v4: format detect + compaction scan (pad to 128) ----------------
__global__ __launch_bounds__(256) void mask_prep(const unsigned char* __restrict__ mraw,
                                                 _Float16* __restrict__ maskc,
                                                 float* __restrict__ qmask,
                                                 int* __restrict__ ks,
                                                 int* __restrict__ nkpa) {
  __shared__ int flags[2];
  __shared__ int psum[256];
  const int b = blockIdx.x, tid = threadIdx.x;
  if (tid < 2) flags[tid] = 1;
  __syncthreads();
  const unsigned int* w = (const unsigned int*)mraw;
  for (int i = tid; i < 2048; i += 256) {  // first 8KiB format scan
    unsigned int v = w[i];
    if (!(v == 0u || v == 1u)) flags[0] = 0;
    if (!(v == 0u || v == 0x3f800000u)) flags[1] = 0;
  }
  __syncthreads();
  const int is_i32 = flags[0], is_f32 = flags[1];
  int m[8]; int cnt = 0;
  for (int i = 0; i < 8; ++i) {
    const int idx = b * 2048 + tid * 8 + i;
    int mv;
    if (is_i32)      mv = ((const int*)mraw)[idx];
    else if (is_f32) mv = (((const unsigned int*)mraw)[idx] != 0u);
    else             mv = (mraw[idx] != 0);
    m[i] = mv; cnt += mv;
    qmask[idx] = mv ? 1.0f : 0.0f;
  }
  psum[tid] = cnt;
  __syncthreads();
  for (int off = 1; off < 256; off <<= 1) {
    int u = (tid >= off) ? psum[tid - off] : 0;
    __syncthreads();
    psum[tid] += u;
    __syncthreads();
  }
  const int total = psum[255];
  int base = psum[tid] - cnt;  // exclusive prefix
  for (int i = 0; i < 8; ++i)
    if (m[i]) ks[b * 2048 + (base++)] = tid * 8 + i;
  for (int j = tid; j < 2048; j += 256)
    maskc[b * 2048 + j] = (j < total) ? (_Float16)0.0f : (_Float16)(-60000.0f);
  __syncthreads();
  const int lastv = (total > 0) ? ks[b * 2048 + total - 1] : 0;
  for (int j = total + tid; j < 2048; j += 256)
    ks[b * 2048 + j] = lastv;
  if (tid == 0) nkpa[b] = (total + 127) & ~127;
}

// ---------------- gather-convert x rows into compacted xc (f16) ----------------
__global__ __launch_bounds__(256) void cvt_xc(const float* __restrict__ x,
                                              const int* __restrict__ ks,
                                              const int* __restrict__ nkpa,
                                              _Float16* __restrict__ xc) {
  const int b = blockIdx.y, j = blockIdx.x;
  if (j >= nkpa[b]) return;
  const int s = ks[b * 2048 + j];
  const float* src = x + (size_t)(b * 2048 + s) * E_;
  _Float16* dst = xc + (size_t)(b * 2048 + j) * E_;
  const int i = threadIdx.x * 4;
  float4 v = *(const float4*)(src + i);
  half4v o;
  o[0] = (_Float16)v.x; o[1] = (_Float16)v.y; o[2] = (_Float16)v.z; o[3] = (_Float16)v.w;
  *(half4v*)(dst + i) = o;
}

// ---------------- GEMM staging: 128 rows x 32 f16 cols -> LDS (linear) ----------------
__device__ __forceinline__ void stage128x32(const _Float16* __restrict__ g, int ld,
                                            _Float16* lds, int wid, int lane) {
#pragma unroll
  for (int j = 0; j < 2; ++j) {
    const int c = j * 256 + wid * 64 + lane;
    const _Float16* src = g + (size_t)(c >> 2) * ld + (c & 3) * 8;
    _Float16* dst = lds + (size_t)(j * 256 + wid * 64) * 8;
    __builtin_amdgcn_global_load_lds((gconst_void*)src, (lds_void*)dst, 16, 0, 0);
  }
}

// ---------------- QKV projection GEMM on COMPACTED rows, anti-aliased 1D grid ----------------
// id decode: tt = id/96 (CU-stride 256 -> tt jumps ~2.7: balanced active/inactive mix per CU).
__global__ __launch_bounds__(256) void qkv_gemm(
    const _Float16* __restrict__ xc, const int* __restrict__ nkpa,
    const _Float16* __restrict__ wq, const _Float16* __restrict__ wk, const _Float16* __restrict__ wv,
    const float* __restrict__ bq, const float* __restrict__ bkp, const float* __restrict__ bvp,
    _Float16* __restrict__ Qc, _Float16* __restrict__ Kc, _Float16* __restrict__ Vc) {
  const int id = blockIdx.x;
  const int tt = id / 96;
  const int rem = id % 96;
  const int bb = rem / 24;
  const int r2 = rem % 24;
  const int by = r2 / 3, z = r2 % 3;
  if (tt * 128 >= nkpa[bb]) return;  // block-uniform exit before any barrier
  __shared__ _Float16 As[128 * 32];
  __shared__ _Float16 Bs[128 * 32];
  const int tid = threadIdx.x, lane = tid & 63, wid = tid >> 6;
  const int g = lane >> 4, r16 = lane & 15;
  const int bm = (bb * 16 + tt) * 128, bn = by * 128;
  const _Float16* w = (z == 0) ? wq : (z == 1) ? wk : wv;
  const float* bias = (z == 0) ? bq : (z == 1) ? bkp : bvp;
  const int wr = wid >> 1, wc = wid & 1;
  f32x4 acc[4][4] = {};
  for (int k0 = 0; k0 < E_; k0 += 32) {
    stage128x32(xc + (size_t)bm * E_ + k0, E_, As, wid, lane);
    stage128x32(w + (size_t)bn * E_ + k0, E_, Bs, wid, lane);
    __syncthreads();
    half8v a[4], bf[4];
#pragma unroll
    for (int i = 0; i < 4; ++i) a[i] = *(const half8v*)&As[(wr * 64 + i * 16 + r16) * 32 + g * 8];
#pragma unroll
    for (int i = 0; i < 4; ++i) bf[i] = *(const half8v*)&Bs[(wc * 64 + i * 16 + r16) * 32 + g * 8];
#pragma unroll
    for (int i = 0; i < 4; ++i)
#pragma unroll
      for (int j = 0; j < 4; ++j) acc[i][j] = MFMA16(a[i], bf[j], acc[i][j]);
    __syncthreads();
  }
#pragma unroll
  for (int i = 0; i < 4; ++i) {
#pragma unroll
    for (int j = 0; j < 4; ++j) {
      const int gn = bn + wc * 64 + j * 16 + r16;
      const float bb2 = bias[gn];
      const int h = gn >> 6, d = gn & 63;
      const int gm0 = bm + wr * 64 + i * 16 + g * 4;
      const int b_ = gm0 >> 11, s0 = gm0 & (S_ - 1);
      const size_t bhbase = (size_t)(b_ * H_ + h) * S_ * D_;
      if (z == 2) {
        half4v v4;
#pragma unroll
        for (int ii = 0; ii < 4; ++ii) v4[ii] = (_Float16)(acc[i][j][ii] + bb2);
        *(half4v*)&Vc[bhbase + (size_t)(s0 >> 4) * (D_ * 16) + d * 16 + (s0 & 15)] = v4;
      } else if (z == 1) {
#pragma unroll
        for (int ii = 0; ii < 4; ++ii) {
          const int s = s0 + ii;
          Kc[bhbase + (size_t)(s >> 5) * 2048 + (d >> 4) * 512 + (s & 31) * 16 + (d & 15)] =
              (_Float16)(acc[i][j][ii] + bb2);
        }
      } else {
#pragma unroll
        for (int ii = 0; ii < 4; ++ii)
          Qc[bhbase + (size_t)(s0 + ii) * D_ + d] = (_Float16)((acc[i][j][ii] + bb2) * QSCALE);
      }
    }
  }
}

// ---------------- flash attention v14: compacted, anti-aliased decode, compacted O ----------------
// id decode: slot = id&7 (XCD/head locality), hbh = (id>>3)&7, t = id>>6 (CU-stride 256 -> t += 4).
__global__ __launch_bounds__(512) void attn_kernel(
    const _Float16* __restrict__ Qc, const _Float16* __restrict__ Kc, const _Float16* __restrict__ Vc,
    const _Float16* __restrict__ maskc, const int* __restrict__ nkpa,
    _Float16* __restrict__ Oc) {
  __shared__ float mlds[4][64][36];  // merge buffer; first 4KB aliased as mask row during loop
  _Float16* smask = (_Float16*)&mlds[0][0][0];
  const int tid = threadIdx.x, lane = tid & 63, wid = tid >> 6;
  const int c = lane & 31, hi = lane >> 5;
  const int qg = wid & 3, kh = wid >> 2;
  const int id = blockIdx.x;
  const int slot = id & 7, hbh = (id >> 3) & 7, t = id >> 6;
  const int hb = hbh * 8 + slot;
  const int b = hb >> 4, h = hb & 15;
  const int nkp = nkpa[b];
  if (t * 128 >= nkp) return;  // block-uniform early exit (before any barrier)
  const size_t bh = (size_t)(b * H_ + h);
  const _Float16* Qb = Qc + bh * S_ * D_;
  const _Float16* Kb = Kc + bh * S_ * D_;
  const _Float16* Vb = Vc + bh * S_ * D_;

  // stage compacted mask row (2048 f16 = 4KB) into LDS
  *((half4v*)smask + tid) = *((const half4v*)(maskc + (size_t)b * S_) + tid);

  const int jq = t * 128 + qg * 32 + c;      // compacted q row

  // Q B-frags (pre-scaled): col=q, kdim d = 16*kc + 8*hi + j
  half8v qb[4];
#pragma unroll
  for (int kc = 0; kc < 4; ++kc)
    qb[kc] = *(const half8v*)&Qb[(size_t)jq * D_ + 16 * kc + 8 * hi];

  half8v bone = {};
  if (hi == 0) bone[0] = (_Float16)1.0f;  // B[kdim=0][q]=1 for rank-1 mask MFMA
  const f32x16 fzero = {};

  f32x16 oacc[2] = {};  // out^T[d][q]
  float mrun = -1e30f, lrun = 0.f;  // lrun is PER-HALF partial until after the loop
  const int laneoff = c * 16 + 8 * hi;
  const int nkh = nkp >> 1;
  const int kb0 = kh * nkh;

  __syncthreads();  // mask staged

  // prefetch iter-0 K frags + mask value
  half8v kaf[4];
  {
    const _Float16* ktb = Kb + (size_t)(kb0 >> 5) * 2048 + laneoff;
#pragma unroll
    for (int kc = 0; kc < 4; ++kc) kaf[kc] = *(const half8v*)&ktb[kc * 512];
  }
  _Float16 mv = smask[kb0 + c];

  for (int kb = kb0; kb < kb0 + nkh; kb += 32) {
    // ---- QK^T from register-resident fragments ----
    half8v amask = {};
    if (hi == 0) amask[0] = mv;
    __builtin_amdgcn_s_setprio(1);
    f32x16 sc = MFMA32(amask, bone, fzero);
    sc = MFMA32(kaf[0], qb[0], sc);
    sc = MFMA32(kaf[1], qb[1], sc);
    sc = MFMA32(kaf[2], qb[2], sc);
    sc = MFMA32(kaf[3], qb[3], sc);
    __builtin_amdgcn_s_setprio(0);
    // ---- prefetch next-iter K frags + mask; V frags for this iter ----
    const int kbn = (kb + 32 < kb0 + nkh) ? kb + 32 : kb0;
    {
      const _Float16* ktb = Kb + (size_t)(kbn >> 5) * 2048 + laneoff;
#pragma unroll
      for (int kc = 0; kc < 4; ++kc) kaf[kc] = *(const half8v*)&ktb[kc * 512];
    }
    mv = smask[kbn + c];
    const _Float16* v_base = Vb + (size_t)(kb >> 4) * (D_ * 16) + laneoff;
    half8v va00 = *(const half8v*)&v_base[0];
    half8v va01 = *(const half8v*)&v_base[512];
    half8v va10 = *(const half8v*)&v_base[1024];
    half8v va11 = *(const half8v*)&v_base[1024 + 512];
    // ---- row max ----
    float t0 = fmaxf(sc[0], sc[4]), t1 = fmaxf(sc[1], sc[5]);
    float t2 = fmaxf(sc[2], sc[6]), t3 = fmaxf(sc[3], sc[7]);
    t0 = fmaxf(fmaxf(sc[8], sc[12]), t0);
    t1 = fmaxf(fmaxf(sc[9], sc[13]), t1);
    t2 = fmaxf(fmaxf(sc[10], sc[14]), t2);
    t3 = fmaxf(fmaxf(sc[11], sc[15]), t3);
    float pmax = fmaxf(fmaxf(t0, t1), fmaxf(t2, t3));
    pmax = fmaxf(pmax, partner32(pmax, hi));
    // ---- defer-max rescale (T13, log2 units) ----
    if (__any(pmax > mrun + 11.0f)) {
      float mnew = fmaxf(mrun, pmax);
      float corr = __builtin_amdgcn_exp2f(mrun - mnew);
      mrun = mnew;
      lrun *= corr;
#pragma unroll
      for (int dt = 0; dt < 2; ++dt)
#pragma unroll
        for (int r = 0; r < 16; ++r) oacc[dt][r] *= corr;
    }
    // ---- FUSED: exp2 + pack + permlane + PV ----
    float ps0 = 0.f, ps1 = 0.f;
#pragma unroll
    for (int sl = 0; sl < 2; ++sl) {
      const int bs = 8 * sl;
      float p0 = __builtin_amdgcn_exp2f(sc[bs + 0] - mrun);
      float p1 = __builtin_amdgcn_exp2f(sc[bs + 1] - mrun);
      float p2 = __builtin_amdgcn_exp2f(sc[bs + 2] - mrun);
      float p3 = __builtin_amdgcn_exp2f(sc[bs + 3] - mrun);
      float p4 = __builtin_amdgcn_exp2f(sc[bs + 4] - mrun);
      float p5 = __builtin_amdgcn_exp2f(sc[bs + 5] - mrun);
      float p6 = __builtin_amdgcn_exp2f(sc[bs + 6] - mrun);
      float p7 = __builtin_amdgcn_exp2f(sc[bs + 7] - mrun);
      ps0 += (p0 + p1) + (p2 + p3);
      ps1 += (p4 + p5) + (p6 + p7);
      unsigned uA = cvt_pk_u32(p0, p1);
      unsigned uB = cvt_pk_u32(p2, p3);
      unsigned uC = cvt_pk_u32(p4, p5);
      unsigned uD = cvt_pk_u32(p6, p7);
      unsigned w0, w1, w2, w3;
      pl32_swap(uA, uC, w0, w2);
      pl32_swap(uB, uD, w1, w3);
      uint4v u4 = {w0, w1, w2, w3};
      half8v pb = __builtin_bit_cast(half8v, u4);
      __builtin_amdgcn_s_setprio(1);
      oacc[0] = MFMA32(sl ? va10 : va00, pb, oacc[0]);
      oacc[1] = MFMA32(sl ? va11 : va01, pb, oacc[1]);
      __builtin_amdgcn_s_setprio(0);
    }
    lrun += ps0 + ps1;
  }
  // ---- cross-half lrun reduction (once) ----
  lrun += partner32(lrun, hi);
  // ---- k-split merge ----
  __syncthreads();
  if (kh == 1) {
    float* p = &mlds[qg][lane][0];
#pragma unroll
    for (int dt = 0; dt < 2; ++dt)
#pragma unroll
      for (int rr = 0; rr < 4; ++rr) {
        float4 v4 = make_float4(oacc[dt][4 * rr], oacc[dt][4 * rr + 1],
                                oacc[dt][4 * rr + 2], oacc[dt][4 * rr + 3]);
        *(float4*)&p[dt * 16 + rr * 4] = v4;
      }
    p[32] = mrun;
    p[33] = lrun;
  }
  __syncthreads();
  if (kh == 0) {
    const float* p = &mlds[qg][lane][0];
    const float mB = p[32], lB = p[33];
    const float mS = fmaxf(mrun, mB);
    const float cA = __builtin_amdgcn_exp2f(mrun - mS);
    const float cB = __builtin_amdgcn_exp2f(mB - mS);
    const float inv = 1.0f / (lrun * cA + lB * cB);
    const float fA = cA * inv, fB = cB * inv;
    _Float16* orow = Oc + ((size_t)(b * S_ + jq)) * E_ + h * D_;  // compacted O
#pragma unroll
    for (int dt = 0; dt < 2; ++dt)
#pragma unroll
      for (int rr = 0; rr < 4; ++rr) {
        float4 vB = *(const float4*)&p[dt * 16 + rr * 4];
        half4v o4;
        o4[0] = (_Float16)(oacc[dt][4 * rr + 0] * fA + vB.x * fB);
        o4[1] = (_Float16)(oacc[dt][4 * rr + 1] * fA + vB.y * fB);
        o4[2] = (_Float16)(oacc[dt][4 * rr + 2] * fA + vB.z * fB);
        o4[3] = (_Float16)(oacc[dt][4 * rr + 3] * fA + vB.w * fB);
        *(half4v*)&orow[32 * dt + 8 * rr + 4 * hi] = o4;
      }
  }
}

// ---------------- output projection on compacted rows + row scatter, fp32 out ----------------
// id decode: tt = id/32, bb = (id%32)/8, by = id%8 -> CU-stride 256 flips tt by 8: balanced.
__global__ __launch_bounds__(256) void oproj_gemm(
    const _Float16* __restrict__ Oc, const _Float16* __restrict__ wo, const float* __restrict__ bo,
    const int* __restrict__ ks, const int* __restrict__ nkpa, float* __restrict__ out) {
  const int id = blockIdx.x;
  const int tt = id / 32;
  const int rem = id % 32;
  const int bb = rem / 8, by = rem % 8;
  if (tt * 128 >= nkpa[bb]) return;
  __shared__ _Float16 As[128 * 32];
  __shared__ _Float16 Bs[128 * 32];
  const int tid = threadIdx.x, lane = tid & 63, wid = tid >> 6;
  const int g = lane >> 4, r16 = lane & 15;
  const int bm = (bb * 16 + tt) * 128, bn = by * 128;
  const int wr = wid >> 1, wc = wid & 1;
  f32x4 acc[4][4] = {};
  for (int k0 = 0; k0 < E_; k0 += 32) {
    stage128x32(Oc + (size_t)bm * E_ + k0, E_, As, wid, lane);
    stage128x32(wo + (size_t)bn * E_ + k0, E_, Bs, wid, lane);
    __syncthreads();
    half8v a[4], bf[4];
#pragma unroll
    for (int i = 0; i < 4; ++i) a[i] = *(const half8v*)&As[(wr * 64 + i * 16 + r16) * 32 + g * 8];
#pragma unroll
    for (int i = 0; i < 4; ++i) bf[i] = *(const half8v*)&Bs[(wc * 64 + i * 16 + r16) * 32 + g * 8];
#pragma unroll
    for (int i = 0; i < 4; ++i)
#pragma unroll
      for (int j = 0; j < 4; ++j) acc[i][j] = MFMA16(a[i], bf[j], acc[i][j]);
    __syncthreads();
  }
#pragma unroll
  for (int i = 0; i < 4; ++i) {
#pragma unroll
    for (int j = 0; j < 4; ++j) {
      const int gn = bn + wc * 64 + j * 16 + r16;
      const float bb2 = bo[gn];
      const int gm0 = bm + wr * 64 + i * 16 + g * 4;
#pragma unroll
      for (int ii = 0; ii < 4; ++ii) {
        const int gm = gm0 + ii;
        const int b_ = gm >> 11, j_ = gm & (S_ - 1);
        const int sorig = ks[b_ * 2048 + j_];  // scatter to original row (pads: dup value, benign)
        const float y = acc[i][j][ii] + bb2;
        out[((size_t)(b_ * S_ + sorig)) * E_ + gn] = fabsf(y);
      }
    }
  }
}

extern "C" void kernel_launch(void* const* d_in, const int* in_sizes, int n_in,
                              void* d_out, int out_size, void* d_ws, size_t ws_size,
                              hipStream_t stream) {
  const float* x = (const float*)d_in[0];
  const unsigned char* mask = (const unsigned char*)d_in[1];
  const float* WQ_w = (const float*)d_in[2];
  const float* WQ_b = (const float*)d_in[3];
  const float* WK_w = (const float*)d_in[4];
  const float* WK_b = (const float*)d_in[5];
  const float* WV_w = (const float*)d_in[6];
  const float* WV_b = (const float*)d_in[7];
  const float* WO_w = (const float*)d_in[8];
  const float* WO_b = (const float*)d_in[9];

  char* ws = (char*)d_ws;
  size_t off = 0;
  _Float16* xc  = (_Float16*)(ws + off); off += (size_t)MTOT * E_ * 2;  // compacted x (f16)
  _Float16* wqh = (_Float16*)(ws + off); off += (size_t)E_ * E_ * 2;
  _Float16* wkh = (_Float16*)(ws + off); off += (size_t)E_ * E_ * 2;
  _Float16* wvh = (_Float16*)(ws + off); off += (size_t)E_ * E_ * 2;
  _Float16* woh = (_Float16*)(ws + off); off += (size_t)E_ * E_ * 2;
  _Float16* Qc  = (_Float16*)(ws + off); off += (size_t)MTOT * E_ * 2;
  _Float16* Kc  = (_Float16*)(ws + off); off += (size_t)MTOT * E_ * 2;
  _Float16* Vc  = (_Float16*)(ws + off); off += (size_t)MTOT * E_ * 2;
  _Float16* Oc  = (_Float16*)(ws + off); off += (size_t)MTOT * E_ * 2;
  _Float16* maskcf = (_Float16*)(ws + off); off += (size_t)B_ * S_ * 2;
  float* qmaskf = (float*)(ws + off); off += (size_t)B_ * S_ * 4;
  int* ksl      = (int*)(ws + off); off += (size_t)B_ * S_ * 4;
  int* nkpa     = (int*)(ws + off); off += 64;
  if (ws_size < off) return;

  const int NW = E_ * E_;     // 1048576
  mask_prep<<<dim3(B_), dim3(256), 0, stream>>>(mask, maskcf, qmaskf, ksl, nkpa);
  cvt_w4<<<dim3(NW / 4 / 256, 4), dim3(256), 0, stream>>>(WQ_w, WK_w, WV_w, WO_w,
                                                          wqh, wkh, wvh, woh);
  cvt_xc<<<dim3(S_, B_), dim3(256), 0, stream>>>(x, ksl, nkpa, xc);
  zero_out<<<dim3(MTOT * E_ / 4 / 256), dim3(256), 0, stream>>>((float*)d_out);
  qkv_gemm<<<dim3(16 * B_ * 8 * 3), dim3(256), 0, stream>>>(
      xc, nkpa, wqh, wkh, wvh, WQ_b, WK_b, WV_b, Qc, Kc, Vc);
  attn_kernel<<<dim3((S_ / 128) * H_ * B_), dim3(512), 0, stream>>>(
      Qc, Kc, Vc, maskcf, nkpa, Oc);
  oproj_gemm<<<dim3(16 * B_ * 8), dim3(256), 0, stream>>>(Oc, woh, WO_b, ksl, nkpa, (float*)d_out);
}

// Round 18
// 144.946 us; speedup vs baseline: 1.7965x; 1.0389x over previous
//
#include <hip/hip_runtime.h>
#include <math.h>

#define B_ 4
#define S_ 2048
#define E_ 1024
#define H_ 16
#define D_ 64
#define MTOT (B_*S_)

typedef _Float16 half8v __attribute__((ext_vector_type(8)));
typedef _Float16 half4v __attribute__((ext_vector_type(4)));
typedef float f32x4 __attribute__((ext_vector_type(4)));
typedef float f32x16 __attribute__((ext_vector_type(16)));
typedef unsigned uint4v __attribute__((ext_vector_type(4)));

typedef __attribute__((address_space(1))) const void gconst_void;
typedef __attribute__((address_space(3))) void lds_void;

#define MFMA16(a,b,c) __builtin_amdgcn_mfma_f32_16x16x32_f16((a),(b),(c),0,0,0)
#define MFMA32(a,b,c) __builtin_amdgcn_mfma_f32_32x32x16_f16((a),(b),(c),0,0,0)

#define QSCALE 0.18033688011112042f  /* 0.125 * log2(e): folded into Q at projection */

static __device__ __forceinline__ unsigned cvt_pk_u32(float a, float b) {
  return __builtin_bit_cast(unsigned, __builtin_amdgcn_cvt_pkrtz(a, b));
}

#if __has_builtin(__builtin_amdgcn_permlane32_swap)
static __device__ __forceinline__ void pl32_swap(unsigned a, unsigned b,
                                                 unsigned& rlo, unsigned& rhi) {
  auto r = __builtin_amdgcn_permlane32_swap(a, b, false, false);
  rlo = r[0]; rhi = r[1];
}
#else
static __device__ __forceinline__ void pl32_swap(unsigned a, unsigned b,
                                                 unsigned& rlo, unsigned& rhi) {
  const int hi = (threadIdx.x & 63) >> 5;
  unsigned t = __shfl_xor(hi ? a : b, 32);
  rlo = hi ? t : a;
  rhi = hi ? b : t;
}
#endif

static __device__ __forceinline__ float partner32(float v, int hi) {
  unsigned u = __builtin_bit_cast(unsigned, v);
  unsigned lo_, hi_;
  pl32_swap(u, u, lo_, hi_);
  return __builtin_bit_cast(float, hi ? lo_ : hi_);
}

// ---------------- fp32 -> fp16 convert, 4 weight matrices in one launch ----------------
__global__ __launch_bounds__(256) void cvt_w4(const float* __restrict__ w0, const float* __restrict__ w1,
                                              const float* __restrict__ w2, const float* __restrict__ w3,
                                              _Float16* __restrict__ o0, _Float16* __restrict__ o1,
                                              _Float16* __restrict__ o2, _Float16* __restrict__ o3) {
  const int z = blockIdx.y;
  const float* in = (z == 0) ? w0 : (z == 1) ? w1 : (z == 2) ? w2 : w3;
  _Float16* out = (z == 0) ? o0 : (z == 1) ? o1 : (z == 2) ? o2 : o3;
  int i = (blockIdx.x * 256 + threadIdx.x) * 4;
  float4 v = *(const float4*)(in + i);
  half4v o;
  o[0] = (_Float16)v.x; o[1] = (_Float16)v.y; o[2] = (_Float16)v.z; o[3] = (_Float16)v.w;
  *(half4v*)(out + i) = o;
}

// ---------------- zero-fill fp32 output ----------------
__global__ __launch_bounds__(256) void zero_out(float* __restrict__ out) {
  const size_t i = ((size_t)blockIdx.x * 256 + threadIdx.x) * 4;
  float4 z = make_float4(0.f, 0.f, 0.f, 0.f);
  *(float4*)(out + i) = z;
}

// ---------------- mask prep v4: format detect + compaction scan (pad to 128) ----------------
__global__ __launch_bounds__(256) void mask_prep(const unsigned char* __restrict__ mraw,
                                                 _Float16* __restrict__ maskc,
                                                 float* __restrict__ qmask,
                                                 int* __restrict__ ks,
                                                 int* __restrict__ nkpa) {
  __shared__ int flags[2];
  __shared__ int psum[256];
  const int b = blockIdx.x, tid = threadIdx.x;
  if (tid < 2) flags[tid] = 1;
  __syncthreads();
  const unsigned int* w = (const unsigned int*)mraw;
  for (int i = tid; i < 2048; i += 256) {  // first 8KiB format scan
    unsigned int v = w[i];
    if (!(v == 0u || v == 1u)) flags[0] = 0;
    if (!(v == 0u || v == 0x3f800000u)) flags[1] = 0;
  }
  __syncthreads();
  const int is_i32 = flags[0], is_f32 = flags[1];
  int m[8]; int cnt = 0;
  for (int i = 0; i < 8; ++i) {
    const int idx = b * 2048 + tid * 8 + i;
    int mv;
    if (is_i32)      mv = ((const int*)mraw)[idx];
    else if (is_f32) mv = (((const unsigned int*)mraw)[idx] != 0u);
    else             mv = (mraw[idx] != 0);
    m[i] = mv; cnt += mv;
    qmask[idx] = mv ? 1.0f : 0.0f;
  }
  psum[tid] = cnt;
  __syncthreads();
  for (int off = 1; off < 256; off <<= 1) {
    int u = (tid >= off) ? psum[tid - off] : 0;
    __syncthreads();
    psum[tid] += u;
    __syncthreads();
  }
  const int total = psum[255];
  int base = psum[tid] - cnt;  // exclusive prefix
  for (int i = 0; i < 8; ++i)
    if (m[i]) ks[b * 2048 + (base++)] = tid * 8 + i;
  for (int j = tid; j < 2048; j += 256)
    maskc[b * 2048 + j] = (j < total) ? (_Float16)0.0f : (_Float16)(-60000.0f);
  __syncthreads();
  const int lastv = (total > 0) ? ks[b * 2048 + total - 1] : 0;
  for (int j = total + tid; j < 2048; j += 256)
    ks[b * 2048 + j] = lastv;
  if (tid == 0) nkpa[b] = (total + 127) & ~127;
}

// ---------------- gather-convert x rows into compacted xc (f16) ----------------
__global__ __launch_bounds__(256) void cvt_xc(const float* __restrict__ x,
                                              const int* __restrict__ ks,
                                              const int* __restrict__ nkpa,
                                              _Float16* __restrict__ xc) {
  const int b = blockIdx.y, j = blockIdx.x;
  if (j >= nkpa[b]) return;
  const int s = ks[b * 2048 + j];
  const float* src = x + (size_t)(b * 2048 + s) * E_;
  _Float16* dst = xc + (size_t)(b * 2048 + j) * E_;
  const int i = threadIdx.x * 4;
  float4 v = *(const float4*)(src + i);
  half4v o;
  o[0] = (_Float16)v.x; o[1] = (_Float16)v.y; o[2] = (_Float16)v.z; o[3] = (_Float16)v.w;
  *(half4v*)(dst + i) = o;
}

// ---------------- GEMM staging: 128 rows x 32 f16 cols -> LDS (linear) ----------------
__device__ __forceinline__ void stage128x32(const _Float16* __restrict__ g, int ld,
                                            _Float16* lds, int wid, int lane) {
#pragma unroll
  for (int j = 0; j < 2; ++j) {
    const int c = j * 256 + wid * 64 + lane;
    const _Float16* src = g + (size_t)(c >> 2) * ld + (c & 3) * 8;
    _Float16* dst = lds + (size_t)(j * 256 + wid * 64) * 8;
    __builtin_amdgcn_global_load_lds((gconst_void*)src, (lds_void*)dst, 16, 0, 0);
  }
}

// ---------------- GEMM staging: 64 rows x 32 f16 cols -> LDS (linear) ----------------
__device__ __forceinline__ void stage64x32(const _Float16* __restrict__ g, int ld,
                                           _Float16* lds, int wid, int lane) {
  const int c = wid * 64 + lane;  // 256 chunks of 16B
  const _Float16* src = g + (size_t)(c >> 2) * ld + (c & 3) * 8;
  _Float16* dst = lds + (size_t)(wid * 64) * 8;
  __builtin_amdgcn_global_load_lds((gconst_void*)src, (lds_void*)dst, 16, 0, 0);
}

// ---------------- QKV projection GEMM, 128x64 tile (6 active blocks/CU) ----------------
// id decode: m = id/48 (CU-stride 256 -> m jumps ~5.3: balanced), r = id%48 -> by(16), z(3).
__global__ __launch_bounds__(256) void qkv_gemm(
    const _Float16* __restrict__ xc, const int* __restrict__ nkpa,
    const _Float16* __restrict__ wq, const _Float16* __restrict__ wk, const _Float16* __restrict__ wv,
    const float* __restrict__ bq, const float* __restrict__ bkp, const float* __restrict__ bvp,
    _Float16* __restrict__ Qc, _Float16* __restrict__ Kc, _Float16* __restrict__ Vc) {
  const int id = blockIdx.x;
  const int m = id / 48;
  const int r = id % 48;
  const int by = r / 3, z = r % 3;
  const int bb = m >> 4, tt = m & 15;
  if (tt * 128 >= nkpa[bb]) return;  // block-uniform exit before any barrier
  __shared__ _Float16 As[128 * 32];
  __shared__ _Float16 Bs[64 * 32];
  const int tid = threadIdx.x, lane = tid & 63, wid = tid >> 6;
  const int g = lane >> 4, r16 = lane & 15;
  const int bm = m * 128, bn = by * 64;
  const _Float16* w = (z == 0) ? wq : (z == 1) ? wk : wv;
  const float* bias = (z == 0) ? bq : (z == 1) ? bkp : bvp;
  const int wr = wid >> 1, wc = wid & 1;
  f32x4 acc[4][2] = {};
  for (int k0 = 0; k0 < E_; k0 += 32) {
    stage128x32(xc + (size_t)bm * E_ + k0, E_, As, wid, lane);
    stage64x32(w + (size_t)bn * E_ + k0, E_, Bs, wid, lane);
    __syncthreads();
    half8v a[4], bf[2];
#pragma unroll
    for (int i = 0; i < 4; ++i) a[i] = *(const half8v*)&As[(wr * 64 + i * 16 + r16) * 32 + g * 8];
#pragma unroll
    for (int j = 0; j < 2; ++j) bf[j] = *(const half8v*)&Bs[(wc * 32 + j * 16 + r16) * 32 + g * 8];
#pragma unroll
    for (int i = 0; i < 4; ++i)
#pragma unroll
      for (int j = 0; j < 2; ++j) acc[i][j] = MFMA16(a[i], bf[j], acc[i][j]);
    __syncthreads();
  }
#pragma unroll
  for (int i = 0; i < 4; ++i) {
#pragma unroll
    for (int j = 0; j < 2; ++j) {
      const int gn = bn + wc * 32 + j * 16 + r16;
      const float bb2 = bias[gn];
      const int h = gn >> 6, d = gn & 63;
      const int gm0 = bm + wr * 64 + i * 16 + g * 4;
      const int b_ = gm0 >> 11, s0 = gm0 & (S_ - 1);
      const size_t bhbase = (size_t)(b_ * H_ + h) * S_ * D_;
      if (z == 2) {
        half4v v4;
#pragma unroll
        for (int ii = 0; ii < 4; ++ii) v4[ii] = (_Float16)(acc[i][j][ii] + bb2);
        *(half4v*)&Vc[bhbase + (size_t)(s0 >> 4) * (D_ * 16) + d * 16 + (s0 & 15)] = v4;
      } else if (z == 1) {
#pragma unroll
        for (int ii = 0; ii < 4; ++ii) {
          const int s = s0 + ii;
          Kc[bhbase + (size_t)(s >> 5) * 2048 + (d >> 4) * 512 + (s & 31) * 16 + (d & 15)] =
              (_Float16)(acc[i][j][ii] + bb2);
        }
      } else {
#pragma unroll
        for (int ii = 0; ii < 4; ++ii)
          Qc[bhbase + (size_t)(s0 + ii) * D_ + d] = (_Float16)((acc[i][j][ii] + bb2) * QSCALE);
      }
    }
  }
}

// ---------------- flash attention v14: compacted, anti-aliased decode, compacted O ----------------
__global__ __launch_bounds__(512) void attn_kernel(
    const _Float16* __restrict__ Qc, const _Float16* __restrict__ Kc, const _Float16* __restrict__ Vc,
    const _Float16* __restrict__ maskc, const int* __restrict__ nkpa,
    _Float16* __restrict__ Oc) {
  __shared__ float mlds[4][64][36];  // merge buffer; first 4KB aliased as mask row during loop
  _Float16* smask = (_Float16*)&mlds[0][0][0];
  const int tid = threadIdx.x, lane = tid & 63, wid = tid >> 6;
  const int c = lane & 31, hi = lane >> 5;
  const int qg = wid & 3, kh = wid >> 2;
  const int id = blockIdx.x;
  const int slot = id & 7, hbh = (id >> 3) & 7, t = id >> 6;
  const int hb = hbh * 8 + slot;
  const int b = hb >> 4, h = hb & 15;
  const int nkp = nkpa[b];
  if (t * 128 >= nkp) return;  // block-uniform early exit (before any barrier)
  const size_t bh = (size_t)(b * H_ + h);
  const _Float16* Qb = Qc + bh * S_ * D_;
  const _Float16* Kb = Kc + bh * S_ * D_;
  const _Float16* Vb = Vc + bh * S_ * D_;

  // stage compacted mask row (2048 f16 = 4KB) into LDS
  *((half4v*)smask + tid) = *((const half4v*)(maskc + (size_t)b * S_) + tid);

  const int jq = t * 128 + qg * 32 + c;      // compacted q row

  // Q B-frags (pre-scaled): col=q, kdim d = 16*kc + 8*hi + j
  half8v qb[4];
#pragma unroll
  for (int kc = 0; kc < 4; ++kc)
    qb[kc] = *(const half8v*)&Qb[(size_t)jq * D_ + 16 * kc + 8 * hi];

  half8v bone = {};
  if (hi == 0) bone[0] = (_Float16)1.0f;  // B[kdim=0][q]=1 for rank-1 mask MFMA
  const f32x16 fzero = {};

  f32x16 oacc[2] = {};  // out^T[d][q]
  float mrun = -1e30f, lrun = 0.f;  // lrun is PER-HALF partial until after the loop
  const int laneoff = c * 16 + 8 * hi;
  const int nkh = nkp >> 1;
  const int kb0 = kh * nkh;

  __syncthreads();  // mask staged

  // prefetch iter-0 K frags + mask value
  half8v kaf[4];
  {
    const _Float16* ktb = Kb + (size_t)(kb0 >> 5) * 2048 + laneoff;
#pragma unroll
    for (int kc = 0; kc < 4; ++kc) kaf[kc] = *(const half8v*)&ktb[kc * 512];
  }
  _Float16 mv = smask[kb0 + c];

  for (int kb = kb0; kb < kb0 + nkh; kb += 32) {
    // ---- QK^T from register-resident fragments ----
    half8v amask = {};
    if (hi == 0) amask[0] = mv;
    __builtin_amdgcn_s_setprio(1);
    f32x16 sc = MFMA32(amask, bone, fzero);
    sc = MFMA32(kaf[0], qb[0], sc);
    sc = MFMA32(kaf[1], qb[1], sc);
    sc = MFMA32(kaf[2], qb[2], sc);
    sc = MFMA32(kaf[3], qb[3], sc);
    __builtin_amdgcn_s_setprio(0);
    // ---- prefetch next-iter K frags + mask; V frags for this iter ----
    const int kbn = (kb + 32 < kb0 + nkh) ? kb + 32 : kb0;
    {
      const _Float16* ktb = Kb + (size_t)(kbn >> 5) * 2048 + laneoff;
#pragma unroll
      for (int kc = 0; kc < 4; ++kc) kaf[kc] = *(const half8v*)&ktb[kc * 512];
    }
    mv = smask[kbn + c];
    const _Float16* v_base = Vb + (size_t)(kb >> 4) * (D_ * 16) + laneoff;
    half8v va00 = *(const half8v*)&v_base[0];
    half8v va01 = *(const half8v*)&v_base[512];
    half8v va10 = *(const half8v*)&v_base[1024];
    half8v va11 = *(const half8v*)&v_base[1024 + 512];
    // ---- row max ----
    float t0 = fmaxf(sc[0], sc[4]), t1 = fmaxf(sc[1], sc[5]);
    float t2 = fmaxf(sc[2], sc[6]), t3 = fmaxf(sc[3], sc[7]);
    t0 = fmaxf(fmaxf(sc[8], sc[12]), t0);
    t1 = fmaxf(fmaxf(sc[9], sc[13]), t1);
    t2 = fmaxf(fmaxf(sc[10], sc[14]), t2);
    t3 = fmaxf(fmaxf(sc[11], sc[15]), t3);
    float pmax = fmaxf(fmaxf(t0, t1), fmaxf(t2, t3));
    pmax = fmaxf(pmax, partner32(pmax, hi));
    // ---- defer-max rescale (T13, log2 units) ----
    if (__any(pmax > mrun + 11.0f)) {
      float mnew = fmaxf(mrun, pmax);
      float corr = __builtin_amdgcn_exp2f(mrun - mnew);
      mrun = mnew;
      lrun *= corr;
#pragma unroll
      for (int dt = 0; dt < 2; ++dt)
#pragma unroll
        for (int r = 0; r < 16; ++r) oacc[dt][r] *= corr;
    }
    // ---- FUSED: exp2 + pack + permlane + PV ----
    float ps0 = 0.f, ps1 = 0.f;
#pragma unroll
    for (int sl = 0; sl < 2; ++sl) {
      const int bs = 8 * sl;
      float p0 = __builtin_amdgcn_exp2f(sc[bs + 0] - mrun);
      float p1 = __builtin_amdgcn_exp2f(sc[bs + 1] - mrun);
      float p2 = __builtin_amdgcn_exp2f(sc[bs + 2] - mrun);
      float p3 = __builtin_amdgcn_exp2f(sc[bs + 3] - mrun);
      float p4 = __builtin_amdgcn_exp2f(sc[bs + 4] - mrun);
      float p5 = __builtin_amdgcn_exp2f(sc[bs + 5] - mrun);
      float p6 = __builtin_amdgcn_exp2f(sc[bs + 6] - mrun);
      float p7 = __builtin_amdgcn_exp2f(sc[bs + 7] - mrun);
      ps0 += (p0 + p1) + (p2 + p3);
      ps1 += (p4 + p5) + (p6 + p7);
      unsigned uA = cvt_pk_u32(p0, p1);
      unsigned uB = cvt_pk_u32(p2, p3);
      unsigned uC = cvt_pk_u32(p4, p5);
      unsigned uD = cvt_pk_u32(p6, p7);
      unsigned w0, w1, w2, w3;
      pl32_swap(uA, uC, w0, w2);
      pl32_swap(uB, uD, w1, w3);
      uint4v u4 = {w0, w1, w2, w3};
      half8v pb = __builtin_bit_cast(half8v, u4);
      __builtin_amdgcn_s_setprio(1);
      oacc[0] = MFMA32(sl ? va10 : va00, pb, oacc[0]);
      oacc[1] = MFMA32(sl ? va11 : va01, pb, oacc[1]);
      __builtin_amdgcn_s_setprio(0);
    }
    lrun += ps0 + ps1;
  }
  // ---- cross-half lrun reduction (once) ----
  lrun += partner32(lrun, hi);
  // ---- k-split merge ----
  __syncthreads();
  if (kh == 1) {
    float* p = &mlds[qg][lane][0];
#pragma unroll
    for (int dt = 0; dt < 2; ++dt)
#pragma unroll
      for (int rr = 0; rr < 4; ++rr) {
        float4 v4 = make_float4(oacc[dt][4 * rr], oacc[dt][4 * rr + 1],
                                oacc[dt][4 * rr + 2], oacc[dt][4 * rr + 3]);
        *(float4*)&p[dt * 16 + rr * 4] = v4;
      }
    p[32] = mrun;
    p[33] = lrun;
  }
  __syncthreads();
  if (kh == 0) {
    const float* p = &mlds[qg][lane][0];
    const float mB = p[32], lB = p[33];
    const float mS = fmaxf(mrun, mB);
    const float cA = __builtin_amdgcn_exp2f(mrun - mS);
    const float cB = __builtin_amdgcn_exp2f(mB - mS);
    const float inv = 1.0f / (lrun * cA + lB * cB);
    const float fA = cA * inv, fB = cB * inv;
    _Float16* orow = Oc + ((size_t)(b * S_ + jq)) * E_ + h * D_;  // compacted O
#pragma unroll
    for (int dt = 0; dt < 2; ++dt)
#pragma unroll
      for (int rr = 0; rr < 4; ++rr) {
        float4 vB = *(const float4*)&p[dt * 16 + rr * 4];
        half4v o4;
        o4[0] = (_Float16)(oacc[dt][4 * rr + 0] * fA + vB.x * fB);
        o4[1] = (_Float16)(oacc[dt][4 * rr + 1] * fA + vB.y * fB);
        o4[2] = (_Float16)(oacc[dt][4 * rr + 2] * fA + vB.z * fB);
        o4[3] = (_Float16)(oacc[dt][4 * rr + 3] * fA + vB.w * fB);
        *(half4v*)&orow[32 * dt + 8 * rr + 4 * hi] = o4;
      }
  }
}

// ---------------- output projection, 64x128 tile (2 active blocks/CU), row scatter ----------------
// id decode: jt = id/32 (CU-stride 256 -> jt jumps 8: balanced), rem -> bb(4), by(8).
__global__ __launch_bounds__(256) void oproj_gemm(
    const _Float16* __restrict__ Oc, const _Float16* __restrict__ wo, const float* __restrict__ bo,
    const int* __restrict__ ks, const int* __restrict__ nkpa, float* __restrict__ out) {
  const int id = blockIdx.x;
  const int jt = id / 32;          // 0..31  (64-row tiles within batch)
  const int rem = id % 32;
  const int bb = rem / 8, by = rem % 8;
  if (jt * 64 >= nkpa[bb]) return;
  __shared__ _Float16 As[64 * 32];
  __shared__ _Float16 Bs[128 * 32];
  const int tid = threadIdx.x, lane = tid & 63, wid = tid >> 6;
  const int g = lane >> 4, r16 = lane & 15;
  const int bm = bb * 2048 + jt * 64, bn = by * 128;
  const int wr = wid >> 1, wc = wid & 1;
  f32x4 acc[2][4] = {};
  for (int k0 = 0; k0 < E_; k0 += 32) {
    stage64x32(Oc + (size_t)bm * E_ + k0, E_, As, wid, lane);
    stage128x32(wo + (size_t)bn * E_ + k0, E_, Bs, wid, lane);
    __syncthreads();
    half8v a[2], bf[4];
#pragma unroll
    for (int i = 0; i < 2; ++i) a[i] = *(const half8v*)&As[(wr * 32 + i * 16 + r16) * 32 + g * 8];
#pragma unroll
    for (int j = 0; j < 4; ++j) bf[j] = *(const half8v*)&Bs[(wc * 64 + j * 16 + r16) * 32 + g * 8];
#pragma unroll
    for (int i = 0; i < 2; ++i)
#pragma unroll
      for (int j = 0; j < 4; ++j) acc[i][j] = MFMA16(a[i], bf[j], acc[i][j]);
    __syncthreads();
  }
#pragma unroll
  for (int i = 0; i < 2; ++i) {
#pragma unroll
    for (int j = 0; j < 4; ++j) {
      const int gn = bn + wc * 64 + j * 16 + r16;
      const float bb2 = bo[gn];
      const int gm0 = bm + wr * 32 + i * 16 + g * 4;
#pragma unroll
      for (int ii = 0; ii < 4; ++ii) {
        const int gm = gm0 + ii;
        const int b_ = gm >> 11, j_ = gm & (S_ - 1);
        const int sorig = ks[b_ * 2048 + j_];  // scatter to original row (pads: dup value, benign)
        const float y = acc[i][j][ii] + bb2;
        out[((size_t)(b_ * S_ + sorig)) * E_ + gn] = fabsf(y);
      }
    }
  }
}

extern "C" void kernel_launch(void* const* d_in, const int* in_sizes, int n_in,
                              void* d_out, int out_size, void* d_ws, size_t ws_size,
                              hipStream_t stream) {
  const float* x = (const float*)d_in[0];
  const unsigned char* mask = (const unsigned char*)d_in[1];
  const float* WQ_w = (const float*)d_in[2];
  const float* WQ_b = (const float*)d_in[3];
  const float* WK_w = (const float*)d_in[4];
  const float* WK_b = (const float*)d_in[5];
  const float* WV_w = (const float*)d_in[6];
  const float* WV_b = (const float*)d_in[7];
  const float* WO_w = (const float*)d_in[8];
  const float* WO_b = (const float*)d_in[9];

  char* ws = (char*)d_ws;
  size_t off = 0;
  _Float16* xc  = (_Float16*)(ws + off); off += (size_t)MTOT * E_ * 2;  // compacted x (f16)
  _Float16* wqh = (_Float16*)(ws + off); off += (size_t)E_ * E_ * 2;
  _Float16* wkh = (_Float16*)(ws + off); off += (size_t)E_ * E_ * 2;
  _Float16* wvh = (_Float16*)(ws + off); off += (size_t)E_ * E_ * 2;
  _Float16* woh = (_Float16*)(ws + off); off += (size_t)E_ * E_ * 2;
  _Float16* Qc  = (_Float16*)(ws + off); off += (size_t)MTOT * E_ * 2;
  _Float16* Kc  = (_Float16*)(ws + off); off += (size_t)MTOT * E_ * 2;
  _Float16* Vc  = (_Float16*)(ws + off); off += (size_t)MTOT * E_ * 2;
  _Float16* Oc  = (_Float16*)(ws + off); off += (size_t)MTOT * E_ * 2;
  _Float16* maskcf = (_Float16*)(ws + off); off += (size_t)B_ * S_ * 2;
  float* qmaskf = (float*)(ws + off); off += (size_t)B_ * S_ * 4;
  int* ksl      = (int*)(ws + off); off += (size_t)B_ * S_ * 4;
  int* nkpa     = (int*)(ws + off); off += 64;
  if (ws_size < off) return;

  const int NW = E_ * E_;     // 1048576
  mask_prep<<<dim3(B_), dim3(256), 0, stream>>>(mask, maskcf, qmaskf, ksl, nkpa);
  cvt_w4<<<dim3(NW / 4 / 256, 4), dim3(256), 0, stream>>>(WQ_w, WK_w, WV_w, WO_w,
                                                          wqh, wkh, wvh, woh);
  cvt_xc<<<dim3(S_, B_), dim3(256), 0, stream>>>(x, ksl, nkpa, xc);
  zero_out<<<dim3(MTOT * E_ / 4 / 256), dim3(256), 0, stream>>>((float*)d_out);
  qkv_gemm<<<dim3(64 * 48), dim3(256), 0, stream>>>(
      xc, nkpa, wqh, wkh, wvh, WQ_b, WK_b, WV_b, Qc, Kc, Vc);
  attn_kernel<<<dim3((S_ / 128) * H_ * B_), dim3(512), 0, stream>>>(
      Qc, Kc, Vc, maskcf, nkpa, Oc);
  oproj_gemm<<<dim3(32 * 32), dim3(256), 0, stream>>>(Oc, woh, WO_b, ksl, nkpa, (float*)d_out);
}